// Round 8
// baseline (1947.886 us; speedup 1.0000x reference)
//
#include <hip/hip_runtime.h>
#include <hip/hip_cooperative_groups.h>
#include <hip/hip_bf16.h>
#include <stdint.h>

typedef _Float16 f16;
typedef __attribute__((ext_vector_type(8))) _Float16 f16x8;
typedef __attribute__((ext_vector_type(4))) _Float16 f16x4;
typedef __attribute__((ext_vector_type(4))) float f32x4;

#define GLOBAL_AS __attribute__((address_space(1)))
#define LDS_AS __attribute__((address_space(3)))

#define D_DIM 768
#define NTOK 1024
#define NSLOT 16
#define NB 32
#define NTOT (NB*NTOK)   // 32768
#define HDIM 512
#define INNER 3072
#define SCALE_D 0.03608439182435161f   // 768^-0.5
#define SCALE_H 0.125f                 // 64^-0.5

// ================= standalone kernels (setup + fallback path, proven R5 bodies) =================

// ---------- MFMA GEMM 64x64, BK=256 ----------
template<int OUT>
__global__ __launch_bounds__(256) void mgemm64_k(
    const f16* __restrict__ A, const f16* __restrict__ Bt,
    void* __restrict__ Cout, int M, int N, int K, int Kc)
{
  __shared__ __align__(16) f16 As[64*256];
  __shared__ __align__(16) f16 Bs[64*256];
  const int tid = threadIdx.x;
  const int lane = tid & 63;
  const int wave = tid >> 6;
  const int m0 = blockIdx.x*64, n0 = blockIdx.y*64;
  const int kbeg = blockIdx.z * Kc;
  const int wm = (wave>>1)*32, wn = (wave&1)*32;
  const int quad = lane>>4, l16 = lane&15;

  const int sr = tid>>2;
  const int sc = (tid&3)*8;
  const f16* gA = A  + (size_t)(m0+sr)*K + kbeg + sc;
  const f16* gB = Bt + (size_t)(n0+sr)*K + kbeg + sc;
  LDS_AS f16* lA = (LDS_AS f16*)&As[(size_t)tid*8];
  LDS_AS f16* lB = (LDS_AS f16*)&Bs[(size_t)tid*8];

  const f16* fA0 = &As[(wm + l16)*32 + quad*8];
  const f16* fB0 = &Bs[(wn + l16)*32 + quad*8];

  f32x4 acc[2][2] = {};

  for (int k0 = 0; k0 < Kc; k0 += 256){
    #pragma unroll
    for (int p=0;p<8;++p){
      __builtin_amdgcn_global_load_lds((const GLOBAL_AS void*)(gA + k0 + p*32),
                                       (LDS_AS void*)(lA + (size_t)p*2048), 16, 0, 0);
      __builtin_amdgcn_global_load_lds((const GLOBAL_AS void*)(gB + k0 + p*32),
                                       (LDS_AS void*)(lB + (size_t)p*2048), 16, 0, 0);
    }
    __syncthreads();
    #pragma unroll
    for (int p=0;p<8;++p){
      f16x8 a0 = *(const f16x8*)(fA0 + p*2048);
      f16x8 a1 = *(const f16x8*)(fA0 + p*2048 + 16*32);
      f16x8 b0 = *(const f16x8*)(fB0 + p*2048);
      f16x8 b1 = *(const f16x8*)(fB0 + p*2048 + 16*32);
      acc[0][0] = __builtin_amdgcn_mfma_f32_16x16x32_f16(a0,b0,acc[0][0],0,0,0);
      acc[0][1] = __builtin_amdgcn_mfma_f32_16x16x32_f16(a0,b1,acc[0][1],0,0,0);
      acc[1][0] = __builtin_amdgcn_mfma_f32_16x16x32_f16(a1,b0,acc[1][0],0,0,0);
      acc[1][1] = __builtin_amdgcn_mfma_f32_16x16x32_f16(a1,b1,acc[1][1],0,0,0);
    }
    __syncthreads();
  }
  #pragma unroll
  for (int mt=0;mt<2;++mt){
    #pragma unroll
    for (int nt=0;nt<2;++nt){
      int gm = m0 + wm + mt*16 + quad*4;
      int gn = n0 + wn + nt*16 + l16;
      #pragma unroll
      for (int r=0;r<4;++r){
        float c = acc[mt][nt][r];
        size_t idx = (size_t)(gm+r)*N + gn;
        if (OUT==0)      ((float*)Cout)[idx] = c;
        else if (OUT==1) ((f16*)Cout)[idx] = (f16)c;
        else             atomicAdd(&((float*)Cout)[idx], c);
      }
    }
  }
}

// ---------- W1 + GLU fused ----------
__global__ __launch_bounds__(256) void w1glu_k(
    const f16* __restrict__ A, const f16* __restrict__ W1T,
    f16* __restrict__ act, int M)
{
  __shared__ __align__(16) f16 As[64*128];
  __shared__ __align__(16) f16 Bu[64*128];
  __shared__ __align__(16) f16 Bg[64*128];
  const int K = 768;
  const int tid = threadIdx.x;
  const int lane = tid & 63;
  const int wave = tid >> 6;
  const int m0 = blockIdx.x*64, n0 = blockIdx.y*64;
  const int wm = (wave>>1)*32, wn = (wave&1)*32;
  const int quad = lane>>4, l16 = lane&15;

  const int sr = tid>>2;
  const int sc = (tid&3)*8;
  const f16* gA  = A   + (size_t)(m0+sr)*K + sc;
  const f16* gBu = W1T + (size_t)(n0+sr)*K + sc;
  const f16* gBg = W1T + (size_t)(3072+n0+sr)*K + sc;
  LDS_AS f16* lA  = (LDS_AS f16*)&As[(size_t)tid*8];
  LDS_AS f16* lBu = (LDS_AS f16*)&Bu[(size_t)tid*8];
  LDS_AS f16* lBg = (LDS_AS f16*)&Bg[(size_t)tid*8];

  const f16* fA0 = &As[(wm + l16)*32 + quad*8];
  const f16* fU0 = &Bu[(wn + l16)*32 + quad*8];
  const f16* fG0 = &Bg[(wn + l16)*32 + quad*8];

  f32x4 accU[2][2] = {};
  f32x4 accG[2][2] = {};

  for (int k0 = 0; k0 < K; k0 += 128){
    #pragma unroll
    for (int p=0;p<4;++p){
      __builtin_amdgcn_global_load_lds((const GLOBAL_AS void*)(gA  + k0 + p*32),
                                       (LDS_AS void*)(lA  + (size_t)p*2048), 16, 0, 0);
      __builtin_amdgcn_global_load_lds((const GLOBAL_AS void*)(gBu + k0 + p*32),
                                       (LDS_AS void*)(lBu + (size_t)p*2048), 16, 0, 0);
      __builtin_amdgcn_global_load_lds((const GLOBAL_AS void*)(gBg + k0 + p*32),
                                       (LDS_AS void*)(lBg + (size_t)p*2048), 16, 0, 0);
    }
    __syncthreads();
    #pragma unroll
    for (int p=0;p<4;++p){
      f16x8 a0 = *(const f16x8*)(fA0 + p*2048);
      f16x8 a1 = *(const f16x8*)(fA0 + p*2048 + 16*32);
      f16x8 u0 = *(const f16x8*)(fU0 + p*2048);
      f16x8 u1 = *(const f16x8*)(fU0 + p*2048 + 16*32);
      f16x8 g0 = *(const f16x8*)(fG0 + p*2048);
      f16x8 g1 = *(const f16x8*)(fG0 + p*2048 + 16*32);
      accU[0][0] = __builtin_amdgcn_mfma_f32_16x16x32_f16(a0,u0,accU[0][0],0,0,0);
      accU[0][1] = __builtin_amdgcn_mfma_f32_16x16x32_f16(a0,u1,accU[0][1],0,0,0);
      accU[1][0] = __builtin_amdgcn_mfma_f32_16x16x32_f16(a1,u0,accU[1][0],0,0,0);
      accU[1][1] = __builtin_amdgcn_mfma_f32_16x16x32_f16(a1,u1,accU[1][1],0,0,0);
      accG[0][0] = __builtin_amdgcn_mfma_f32_16x16x32_f16(a0,g0,accG[0][0],0,0,0);
      accG[0][1] = __builtin_amdgcn_mfma_f32_16x16x32_f16(a0,g1,accG[0][1],0,0,0);
      accG[1][0] = __builtin_amdgcn_mfma_f32_16x16x32_f16(a1,g0,accG[1][0],0,0,0);
      accG[1][1] = __builtin_amdgcn_mfma_f32_16x16x32_f16(a1,g1,accG[1][1],0,0,0);
    }
    __syncthreads();
  }
  #pragma unroll
  for (int mt=0;mt<2;++mt){
    #pragma unroll
    for (int nt=0;nt<2;++nt){
      int gm = m0 + wm + mt*16 + quad*4;
      int gn = n0 + wn + nt*16 + l16;
      #pragma unroll
      for (int r=0;r<4;++r){
        float u = accU[mt][nt][r];
        float g = accG[mt][nt][r];
        float sg = g / (1.0f + __expf(-g));
        act[(size_t)(gm+r)*INNER + gn] = (f16)(u*sg);
      }
    }
  }
}

// ---------- MFMA dots + inverted softmax + partial rowsum ----------
__global__ __launch_bounds__(256) void dots_k(
    const f16* __restrict__ Q, const f16* __restrict__ Xn,
    f16* __restrict__ attn, float* __restrict__ rsPart)
{
  __shared__ __align__(16) f16 qf[16*768];
  __shared__ __align__(16) f16 ks[64*256];
  __shared__ float rpart[4][16];
  const int b = blockIdx.x, jt = blockIdx.y;
  const int tid = threadIdx.x;
  const int lane = tid & 63;
  const int w = tid >> 6;
  const int quad = lane>>4, l16 = lane&15;

  #pragma unroll
  for (int c=0;c<6;++c){
    int p = c*256 + tid;
    int ki = p >> 6, qd = (p >> 4) & 3, rw = p & 15;
    f16x8 v = *(const f16x8*)(Q + ((size_t)(b*NSLOT+rw))*D_DIM + ki*32 + qd*8);
    *(f16x8*)&qf[(size_t)p*8] = v;
  }

  const f16* gK = Xn + ((size_t)(b*NTOK + jt*64 + (tid>>2)))*D_DIM + (tid&3)*8;
  LDS_AS f16* lK = (LDS_AS f16*)&ks[(size_t)tid*8];

  f32x4 acc = {};
  for (int it=0; it<3; ++it){
    #pragma unroll
    for (int p=0;p<8;++p)
      __builtin_amdgcn_global_load_lds((const GLOBAL_AS void*)(gK + it*256 + p*32),
                                       (LDS_AS void*)(lK + (size_t)p*2048), 16, 0, 0);
    __syncthreads();
    #pragma unroll
    for (int p=0;p<8;++p){
      f16x8 a  = *(const f16x8*)&qf[(((size_t)(it*8+p)*4 + quad)*16 + l16)*8];
      f16x8 bf = *(const f16x8*)&ks[(size_t)p*2048 + (w*16+l16)*32 + quad*8];
      acc = __builtin_amdgcn_mfma_f32_16x16x32_f16(a, bf, acc, 0, 0, 0);
    }
    __syncthreads();
  }

  float v0 = acc[0]*SCALE_D, v1 = acc[1]*SCALE_D, v2 = acc[2]*SCALE_D, v3 = acc[3]*SCALE_D;
  float mx = fmaxf(fmaxf(v0,v1), fmaxf(v2,v3));
  mx = fmaxf(mx, __shfl_xor(mx, 16));
  mx = fmaxf(mx, __shfl_xor(mx, 32));
  float e0 = __expf(v0-mx), e1 = __expf(v1-mx), e2 = __expf(v2-mx), e3 = __expf(v3-mx);
  float s = e0+e1+e2+e3;
  s += __shfl_xor(s, 16);
  s += __shfl_xor(s, 32);
  float inv = 1.0f/s;
  float a0 = e0*inv + 1e-8f, a1 = e1*inv + 1e-8f, a2 = e2*inv + 1e-8f, a3 = e3*inv + 1e-8f;

  int jcol = jt*64 + w*16 + l16;
  int ibase = b*NSLOT + quad*4;
  attn[(size_t)(ibase+0)*NTOK + jcol] = (f16)a0;
  attn[(size_t)(ibase+1)*NTOK + jcol] = (f16)a1;
  attn[(size_t)(ibase+2)*NTOK + jcol] = (f16)a2;
  attn[(size_t)(ibase+3)*NTOK + jcol] = (f16)a3;

  float t0=a0, t1=a1, t2=a2, t3=a3;
  #pragma unroll
  for (int m=1;m<16;m<<=1){
    t0 += __shfl_xor(t0, m);
    t1 += __shfl_xor(t1, m);
    t2 += __shfl_xor(t2, m);
    t3 += __shfl_xor(t3, m);
  }
  if (l16 == 0){
    rpart[w][quad*4+0] = t0;
    rpart[w][quad*4+1] = t1;
    rpart[w][quad*4+2] = t2;
    rpart[w][quad*4+3] = t3;
  }
  __syncthreads();
  if (tid < 16){
    float ss = rpart[0][tid] + rpart[1][tid] + rpart[2][tid] + rpart[3][tid];
    rsPart[(size_t)((b*16 + jt)<<4) + tid] = ss;
  }
}

// ---------- t = (attn @ xn)/rowsum ----------
__global__ __launch_bounds__(256) void attnv_k(
    const f16* __restrict__ attn, const float* __restrict__ rsPart,
    const f16* __restrict__ XnT, f16* __restrict__ t_out)
{
  __shared__ __align__(16) f16 Asl[16*256];
  __shared__ __align__(16) f16 Bsl[64*256];
  __shared__ float rsum[16];
  const int b = blockIdx.x, d0 = blockIdx.y*64;
  const int tid = threadIdx.x;
  const int lane = tid & 63;
  const int w = tid >> 6;
  const int quad = lane>>4, l16 = lane&15;

  if (tid < 16){
    float s = 0.f;
    #pragma unroll
    for (int jt=0;jt<16;++jt) s += rsPart[(size_t)((b*16 + jt)<<4) + tid];
    rsum[tid] = s;
  }

  const int pa = tid>>6, ta = tid&63;
  const f16* gA = attn + ((size_t)(b*NSLOT + (ta>>2)))*NTOK + (ta&3)*8;
  const f16* gB = XnT + ((size_t)(d0 + (tid>>2)))*NTOT + b*NTOK + (tid&3)*8;
  LDS_AS f16* lB = (LDS_AS f16*)&Bsl[(size_t)tid*8];

  f32x4 acc = {};
  for (int it=0; it<4; ++it){
    #pragma unroll
    for (int q=0;q<2;++q){
      int pq = pa*2 + q;
      __builtin_amdgcn_global_load_lds((const GLOBAL_AS void*)(gA + it*256 + pq*32),
                                       (LDS_AS void*)((LDS_AS f16*)&Asl[(size_t)pq*512 + ta*8]), 16, 0, 0);
    }
    #pragma unroll
    for (int p=0;p<8;++p)
      __builtin_amdgcn_global_load_lds((const GLOBAL_AS void*)(gB + it*256 + p*32),
                                       (LDS_AS void*)(lB + (size_t)p*2048), 16, 0, 0);
    __syncthreads();
    #pragma unroll
    for (int p=0;p<8;++p){
      f16x8 a  = *(const f16x8*)&Asl[(size_t)p*512 + l16*32 + quad*8];
      f16x8 bf = *(const f16x8*)&Bsl[(size_t)p*2048 + (w*16+l16)*32 + quad*8];
      acc = __builtin_amdgcn_mfma_f32_16x16x32_f16(a, bf, acc, 0, 0, 0);
    }
    __syncthreads();
  }
  int dcol = d0 + w*16 + l16;
  #pragma unroll
  for (int r=0;r<4;++r){
    int i = quad*4 + r;
    t_out[(size_t)(b*NSLOT + i)*D_DIM + dcol] = (f16)(acc[r] / rsum[i]);
  }
}

// ---------- wave-per-row LN ----------
__global__ __launch_bounds__(256) void lnw_k(
    const float* __restrict__ X,
    const float* __restrict__ g, const float* __restrict__ bb,
    f16* __restrict__ out)
{
  const int lane = threadIdx.x & 63;
  const size_t row = (size_t)blockIdx.x*4 + (threadIdx.x>>6);
  const float* x = X + row*D_DIM;
  float4 v[3]; float s=0.f, ss=0.f;
  #pragma unroll
  for (int t=0;t<3;++t){
    v[t] = *(const float4*)(x + lane*4 + t*256);
    s  += v[t].x+v[t].y+v[t].z+v[t].w;
    ss += v[t].x*v[t].x+v[t].y*v[t].y+v[t].z*v[t].z+v[t].w*v[t].w;
  }
  #pragma unroll
  for (int m=1;m<64;m<<=1){ s += __shfl_xor(s,m); ss += __shfl_xor(ss,m); }
  float mean = s*(1.0f/768.0f);
  float inv  = rsqrtf(ss*(1.0f/768.0f) - mean*mean + 1e-5f);
  #pragma unroll
  for (int t=0;t<3;++t){
    int c0 = lane*4 + t*256;
    float4 gg = *(const float4*)(g + c0);
    float4 bv = *(const float4*)(bb + c0);
    f16x4 h4;
    h4.x = (f16)((v[t].x-mean)*inv*gg.x + bv.x);
    h4.y = (f16)((v[t].y-mean)*inv*gg.y + bv.y);
    h4.z = (f16)((v[t].z-mean)*inv*gg.z + bv.z);
    h4.w = (f16)((v[t].w-mean)*inv*gg.w + bv.w);
    *(f16x4*)(out + row*D_DIM + c0) = h4;
  }
}

// ---------- wave-per-row double LN ----------
template<bool ADD>
__global__ __launch_bounds__(256) void lnlnw_k(
    const float* __restrict__ X, const float* __restrict__ X2,
    const float* __restrict__ g1, const float* __restrict__ b1,
    const float* __restrict__ g2, const float* __restrict__ b2,
    float* __restrict__ out1, f16* __restrict__ out2)
{
  const int lane = threadIdx.x & 63;
  const size_t row = (size_t)blockIdx.x*4 + (threadIdx.x>>6);
  const float* x = X + row*D_DIM;
  const float* x2 = X2 + row*D_DIM;
  float4 v[3]; float s=0.f, ss=0.f;
  #pragma unroll
  for (int t=0;t<3;++t){
    int c0 = lane*4 + t*256;
    float4 a = *(const float4*)(x + c0);
    if (ADD){
      float4 b = *(const float4*)(x2 + c0);
      a.x+=b.x; a.y+=b.y; a.z+=b.z; a.w+=b.w;
    }
    v[t]=a;
    s  += v[t].x+v[t].y+v[t].z+v[t].w;
    ss += v[t].x*v[t].x+v[t].y*v[t].y+v[t].z*v[t].z+v[t].w*v[t].w;
  }
  #pragma unroll
  for (int m=1;m<64;m<<=1){ s += __shfl_xor(s,m); ss += __shfl_xor(ss,m); }
  float mean = s*(1.0f/768.0f);
  float inv  = rsqrtf(ss*(1.0f/768.0f) - mean*mean + 1e-5f);
  float y[3][4]; float s2=0.f, ss2=0.f;
  #pragma unroll
  for (int t=0;t<3;++t){
    int c0 = lane*4 + t*256;
    float4 gg = *(const float4*)(g1 + c0);
    float4 bv = *(const float4*)(b1 + c0);
    y[t][0] = (v[t].x-mean)*inv*gg.x + bv.x;
    y[t][1] = (v[t].y-mean)*inv*gg.y + bv.y;
    y[t][2] = (v[t].z-mean)*inv*gg.z + bv.z;
    y[t][3] = (v[t].w-mean)*inv*gg.w + bv.w;
    float4 o = { y[t][0], y[t][1], y[t][2], y[t][3] };
    *(float4*)(out1 + row*D_DIM + c0) = o;
    s2  += y[t][0]+y[t][1]+y[t][2]+y[t][3];
    ss2 += y[t][0]*y[t][0]+y[t][1]*y[t][1]+y[t][2]*y[t][2]+y[t][3]*y[t][3];
  }
  #pragma unroll
  for (int m=1;m<64;m<<=1){ s2 += __shfl_xor(s2,m); ss2 += __shfl_xor(ss2,m); }
  float mean2 = s2*(1.0f/768.0f);
  float inv2  = rsqrtf(ss2*(1.0f/768.0f) - mean2*mean2 + 1e-5f);
  #pragma unroll
  for (int t=0;t<3;++t){
    int c0 = lane*4 + t*256;
    float4 gg = *(const float4*)(g2 + c0);
    float4 bv = *(const float4*)(b2 + c0);
    f16x4 h4;
    h4.x = (f16)((y[t][0]-mean2)*inv2*gg.x + bv.x);
    h4.y = (f16)((y[t][1]-mean2)*inv2*gg.y + bv.y);
    h4.z = (f16)((y[t][2]-mean2)*inv2*gg.z + bv.z);
    h4.w = (f16)((y[t][3]-mean2)*inv2*gg.w + bv.w);
    *(f16x4*)(out2 + row*D_DIM + c0) = h4;
  }
}

// ---------- slots init + LN(ns) ----------
__global__ __launch_bounds__(256) void slotsinit_k(
    const float* __restrict__ noise, const float* __restrict__ mu,
    const float* __restrict__ ls,
    const float* __restrict__ nsg, const float* __restrict__ nsb,
    float* __restrict__ slots, f16* __restrict__ tmp2)
{
  const int lane = threadIdx.x & 63;
  const size_t row = (size_t)blockIdx.x*4 + (threadIdx.x>>6);
  float4 v[3]; float s=0.f, ss=0.f;
  #pragma unroll
  for (int t=0;t<3;++t){
    int c0 = lane*4 + t*256;
    float4 nz = *(const float4*)(noise + row*D_DIM + c0);
    float4 m4 = *(const float4*)(mu + c0);
    float4 l4 = *(const float4*)(ls + c0);
    v[t].x = m4.x + __expf(l4.x)*nz.x;
    v[t].y = m4.y + __expf(l4.y)*nz.y;
    v[t].z = m4.z + __expf(l4.z)*nz.z;
    v[t].w = m4.w + __expf(l4.w)*nz.w;
    *(float4*)(slots + row*D_DIM + c0) = v[t];
    s  += v[t].x+v[t].y+v[t].z+v[t].w;
    ss += v[t].x*v[t].x+v[t].y*v[t].y+v[t].z*v[t].z+v[t].w*v[t].w;
  }
  #pragma unroll
  for (int m=1;m<64;m<<=1){ s += __shfl_xor(s,m); ss += __shfl_xor(ss,m); }
  float mean = s*(1.0f/768.0f);
  float inv  = rsqrtf(ss*(1.0f/768.0f) - mean*mean + 1e-5f);
  #pragma unroll
  for (int t=0;t<3;++t){
    int c0 = lane*4 + t*256;
    float4 gg = *(const float4*)(nsg + c0);
    float4 bv = *(const float4*)(nsb + c0);
    f16x4 h4;
    h4.x = (f16)((v[t].x-mean)*inv*gg.x + bv.x);
    h4.y = (f16)((v[t].y-mean)*inv*gg.y + bv.y);
    h4.z = (f16)((v[t].z-mean)*inv*gg.z + bv.z);
    h4.w = (f16)((v[t].w-mean)*inv*gg.w + bv.w);
    *(f16x4*)(tmp2 + row*D_DIM + c0) = h4;
  }
}

// ---------- encoder self-attention ----------
__global__ __launch_bounds__(256) void encattn_k(
    const f16* __restrict__ QA, const f16* __restrict__ KA,
    const f16* __restrict__ VA, int QSTR,
    f16* __restrict__ O)
{
  __shared__ float qs[16][68], ks[16][68], vs[16][68], ps[16][20];
  const int b = blockIdx.x, h = blockIdx.y;
  const int tid = threadIdx.x;
  {
    int i = tid>>4, dd=(tid&15)*4;
    size_t base = ((size_t)(b*NSLOT+i))*QSTR + h*64 + dd;
    f16x4 uq = *(const f16x4*)(QA + base);
    f16x4 uk = *(const f16x4*)(KA + base);
    f16x4 uv = *(const f16x4*)(VA + base);
    float4 fq = { (float)uq.x, (float)uq.y, (float)uq.z, (float)uq.w };
    float4 fk = { (float)uk.x, (float)uk.y, (float)uk.z, (float)uk.w };
    float4 fv = { (float)uv.x, (float)uv.y, (float)uv.z, (float)uv.w };
    *(float4*)&qs[i][dd]=fq; *(float4*)&ks[i][dd]=fk; *(float4*)&vs[i][dd]=fv;
  }
  __syncthreads();
  {
    int i = tid>>4, j = tid&15;
    float s=0.f;
    #pragma unroll 8
    for (int d=0; d<64; ++d) s += qs[i][d]*ks[j][d];
    ps[i][j] = s*SCALE_H;
  }
  __syncthreads();
  if (tid < 16){
    int i = tid;
    float mx=-1e30f;
    #pragma unroll
    for (int j=0;j<16;++j) mx = fmaxf(mx, ps[i][j]);
    float sm=0.f;
    #pragma unroll
    for (int j=0;j<16;++j){ float e=__expf(ps[i][j]-mx); ps[i][j]=e; sm+=e; }
    float inv=1.0f/sm;
    #pragma unroll
    for (int j=0;j<16;++j) ps[i][j]*=inv;
  }
  __syncthreads();
  {
    int i = tid>>4, dq=(tid&15)*4;
    float a0=0,a1=0,a2=0,a3=0;
    #pragma unroll
    for (int j=0;j<16;++j){
      float p = ps[i][j];
      a0+=p*vs[j][dq+0]; a1+=p*vs[j][dq+1]; a2+=p*vs[j][dq+2]; a3+=p*vs[j][dq+3];
    }
    size_t base = ((size_t)(b*NSLOT+i))*HDIM + h*64 + dq;
    O[base+0]=(f16)a0; O[base+1]=(f16)a1; O[base+2]=(f16)a2; O[base+3]=(f16)a3;
  }
}

// ---------- f16 transpose ----------
__global__ __launch_bounds__(256) void transp_k(
    const f16* __restrict__ in, f16* __restrict__ out, int R, int C)
{
  __shared__ f16 T[64][72];
  const int m0 = blockIdx.x*64, d0 = blockIdx.y*64;
  const int tid = threadIdx.x;
  {
    int r = tid>>2, c = (tid&3)*16;
    const f16* p = in + (size_t)(m0+r)*C + d0 + c;
    *(f16x8*)&T[r][c]   = *(const f16x8*)p;
    *(f16x8*)&T[r][c+8] = *(const f16x8*)(p+8);
  }
  __syncthreads();
  {
    int dd = tid>>2, mq = (tid&3)*16;
    f16 v[16];
    #pragma unroll
    for (int e=0;e<16;++e) v[e] = T[mq+e][dd];
    f16* p = out + (size_t)(d0+dd)*R + m0 + mq;
    *(f16x8*)p     = *(f16x8*)&v[0];
    *(f16x8*)(p+8) = *(f16x8*)&v[8];
  }
}

// ---------- weight casts/transposes ----------
__global__ __launch_bounds__(256) void prep_k(
    const float* __restrict__ Wv,   const float* __restrict__ Wq_a,
    const float* __restrict__ Wk_a, const float* __restrict__ Wv_a,
    const float* __restrict__ Wo_a, const float* __restrict__ W1,
    const float* __restrict__ W2,   const float* __restrict__ Wk,
    const float* __restrict__ Wq,
    f16* __restrict__ WvT, f16* __restrict__ WqkvT, f16* __restrict__ WoaT,
    f16* __restrict__ W1T, f16* __restrict__ W2T,
    f16* __restrict__ Wkf, f16* __restrict__ Wqf)
{
  __shared__ float t[32][33];
  int bid = blockIdx.x;
  const float* src; f16* dst; int R, C; bool tr = true;
  if      (bid < 576)  {              src=Wv;   dst=WvT;             R=768;  C=768; }
  else if (bid < 960)  { bid-=576;    src=Wq_a; dst=WqkvT;           R=768;  C=512; }
  else if (bid < 1344) { bid-=960;    src=Wk_a; dst=WqkvT+512*768;   R=768;  C=512; }
  else if (bid < 1728) { bid-=1344;   src=Wv_a; dst=WqkvT+1024*768;  R=768;  C=512; }
  else if (bid < 2112) { bid-=1728;   src=Wo_a; dst=WoaT;            R=512;  C=768; }
  else if (bid < 6720) { bid-=2112;   src=W1;   dst=W1T;             R=768;  C=6144; }
  else if (bid < 9024) { bid-=6720;   src=W2;   dst=W2T;             R=3072; C=768; }
  else if (bid < 9600) { bid-=9024;   src=Wk;   dst=Wkf;             R=768;  C=768; tr=false; }
  else                 { bid-=9600;   src=Wq;   dst=Wqf;             R=768;  C=768; tr=false; }
  const int tpr = C/32;
  const int r0 = (bid / tpr)*32, c0 = (bid % tpr)*32;
  const int lc = threadIdx.x & 31, g8 = threadIdx.x >> 5;
  if (tr){
    #pragma unroll
    for (int s=0;s<4;++s){
      int r = g8*4 + s;
      t[r][lc] = src[(size_t)(r0+r)*C + c0+lc];
    }
    __syncthreads();
    #pragma unroll
    for (int s=0;s<4;++s){
      int c = g8*4 + s;
      dst[(size_t)(c0+c)*R + r0+lc] = (f16)t[lc][c];
    }
  } else {
    #pragma unroll
    for (int s=0;s<4;++s){
      int r = g8*4 + s;
      dst[(size_t)(r0+r)*C + c0+lc] = (f16)src[(size_t)(r0+r)*C + c0+lc];
    }
  }
}

// ---------- attn_map output ----------
__global__ __launch_bounds__(256) void attnout_k(
    const f16* __restrict__ attn, const float* __restrict__ rsPart,
    float* __restrict__ out)
{
  __shared__ float rsum[16];
  const int bid = blockIdx.x, tid = threadIdx.x;
  const int b = bid >> 6;
  if (tid < 16){
    float s = 0.f;
    #pragma unroll
    for (int jt=0;jt<16;++jt) s += rsPart[(size_t)((b*16+jt)<<4) + tid];
    rsum[tid] = s;
  }
  __syncthreads();
  int idx = bid*256 + tid;
  int i = idx & 15;
  int j = (idx >> 4) & 1023;
  out[idx] = (float)attn[((size_t)(b*NSLOT)+i)*NTOK + j] / rsum[i];
}

// ================= mega cooperative kernel (57.6 KB LDS) =================

struct MegaArgs {
  const f16* q; const f16* xn; const f16* xnT;
  f16* attn; float* rsPart; f16* t;
  const f16* WvT; float* upd;
  const float* slots; float* hbuf;
  f16* tmp; f16* tmp2;
  const f16* WqkvT; f16* qkv; f16* o;
  const f16* WoaT; const f16* W1T; f16* act; const f16* W2T;
  const f16* BtQK; f16* qnext; float* out1;
  const float* nica_g; const float* nica_b;
  const float* ln1_g;  const float* ln1_b;
  const float* ln2_g;  const float* ln2_b;
  const float* lnf_g;  const float* lnf_b;
  const float* ns_g;   const float* ns_b;
  int doQnext;
};

// 64x64 GEMM tile body, BK=128 (proven R3 body). OUT: 0 f32, 1 f16, 2 atomicAdd.
template<int OUT>
__device__ __forceinline__ void gemm_tile(
    const f16* __restrict__ A, const f16* __restrict__ Bt, void* __restrict__ Cout,
    int N, int K, int m0, int n0, int kbeg, int Kc, char* smraw, int tid)
{
  f16* As = (f16*)smraw;
  f16* Bs = (f16*)(smraw + 16384);
  const int lane = tid & 63;
  const int wave = tid >> 6;
  const int wm = (wave>>1)*32, wn = (wave&1)*32;
  const int quad = lane>>4, l16 = lane&15;
  const int sr = tid>>2, sc = (tid&3)*8;
  const f16* gA = A  + (size_t)(m0+sr)*K + kbeg + sc;
  const f16* gB = Bt + (size_t)(n0+sr)*K + kbeg + sc;
  LDS_AS f16* lA = (LDS_AS f16*)&As[(size_t)tid*8];
  LDS_AS f16* lB = (LDS_AS f16*)&Bs[(size_t)tid*8];
  const f16* fA0 = &As[(wm + l16)*32 + quad*8];
  const f16* fB0 = &Bs[(wn + l16)*32 + quad*8];
  f32x4 acc[2][2] = {};
  for (int k0 = 0; k0 < Kc; k0 += 128){
    #pragma unroll
    for (int p=0;p<4;++p){
      __builtin_amdgcn_global_load_lds((const GLOBAL_AS void*)(gA + k0 + p*32),
                                       (LDS_AS void*)(lA + (size_t)p*2048), 16, 0, 0);
      __builtin_amdgcn_global_load_lds((const GLOBAL_AS void*)(gB + k0 + p*32),
                                       (LDS_AS void*)(lB + (size_t)p*2048), 16, 0, 0);
    }
    __syncthreads();
    #pragma unroll
    for (int p=0;p<4;++p){
      f16x8 a0 = *(const f16x8*)(fA0 + p*2048);
      f16x8 a1 = *(const f16x8*)(fA0 + p*2048 + 16*32);
      f16x8 b0 = *(const f16x8*)(fB0 + p*2048);
      f16x8 b1 = *(const f16x8*)(fB0 + p*2048 + 16*32);
      acc[0][0] = __builtin_amdgcn_mfma_f32_16x16x32_f16(a0,b0,acc[0][0],0,0,0);
      acc[0][1] = __builtin_amdgcn_mfma_f32_16x16x32_f16(a0,b1,acc[0][1],0,0,0);
      acc[1][0] = __builtin_amdgcn_mfma_f32_16x16x32_f16(a1,b0,acc[1][0],0,0,0);
      acc[1][1] = __builtin_amdgcn_mfma_f32_16x16x32_f16(a1,b1,acc[1][1],0,0,0);
    }
    __syncthreads();
  }
  #pragma unroll
  for (int mt=0;mt<2;++mt){
    #pragma unroll
    for (int nt=0;nt<2;++nt){
      int gm = m0 + wm + mt*16 + quad*4;
      int gn = n0 + wn + nt*16 + l16;
      #pragma unroll
      for (int r=0;r<4;++r){
        float c = acc[mt][nt][r];
        size_t idx = (size_t)(gm+r)*N + gn;
        if (OUT==0)      ((float*)Cout)[idx] = c;
        else if (OUT==1) ((f16*)Cout)[idx] = (f16)c;
        else             atomicAdd(&((float*)Cout)[idx], c);
      }
    }
  }
}

template<bool ADD>
__device__ __forceinline__ void lnln_rows(
    const float* __restrict__ X, const float* __restrict__ X2,
    const float* __restrict__ g1, const float* __restrict__ b1,
    const float* __restrict__ g2, const float* __restrict__ b2,
    float* __restrict__ out1, f16* __restrict__ out2, int gidx, int tid)
{
  const int lane = tid & 63;
  const size_t row = (size_t)gidx*4 + (tid>>6);
  const size_t ro = row*D_DIM;
  float4 v[3]; float s=0.f, ss=0.f;
  #pragma unroll
  for (int t=0;t<3;++t){
    int c0 = lane*4 + t*256;
    float4 a = *(const float4*)(X + ro + c0);
    if (ADD){
      float4 b = *(const float4*)(X2 + ro + c0);
      a.x+=b.x; a.y+=b.y; a.z+=b.z; a.w+=b.w;
    }
    v[t]=a;
    s  += a.x+a.y+a.z+a.w;
    ss += a.x*a.x+a.y*a.y+a.z*a.z+a.w*a.w;
  }
  #pragma unroll
  for (int m=1;m<64;m<<=1){ s += __shfl_xor(s,m); ss += __shfl_xor(ss,m); }
  float mean = s*(1.0f/768.0f);
  float inv  = rsqrtf(ss*(1.0f/768.0f) - mean*mean + 1e-5f);
  float y[3][4]; float s2=0.f, ss2=0.f;
  #pragma unroll
  for (int t=0;t<3;++t){
    int c0 = lane*4 + t*256;
    float4 gg = *(const float4*)(g1 + c0);
    float4 bv = *(const float4*)(b1 + c0);
    y[t][0] = (v[t].x-mean)*inv*gg.x + bv.x;
    y[t][1] = (v[t].y-mean)*inv*gg.y + bv.y;
    y[t][2] = (v[t].z-mean)*inv*gg.z + bv.z;
    y[t][3] = (v[t].w-mean)*inv*gg.w + bv.w;
    float4 o = { y[t][0], y[t][1], y[t][2], y[t][3] };
    *(float4*)(out1 + ro + c0) = o;
    s2  += y[t][0]+y[t][1]+y[t][2]+y[t][3];
    ss2 += y[t][0]*y[t][0]+y[t][1]*y[t][1]+y[t][2]*y[t][2]+y[t][3]*y[t][3];
  }
  #pragma unroll
  for (int m=1;m<64;m<<=1){ s2 += __shfl_xor(s2,m); ss2 += __shfl_xor(ss2,m); }
  float mean2 = s2*(1.0f/768.0f);
  float inv2  = rsqrtf(ss2*(1.0f/768.0f) - mean2*mean2 + 1e-5f);
  #pragma unroll
  for (int t=0;t<3;++t){
    int c0 = lane*4 + t*256;
    float4 gg = *(const float4*)(g2 + c0);
    float4 bv = *(const float4*)(b2 + c0);
    f16x4 h4;
    h4.x = (f16)((y[t][0]-mean2)*inv2*gg.x + bv.x);
    h4.y = (f16)((y[t][1]-mean2)*inv2*gg.y + bv.y);
    h4.z = (f16)((y[t][2]-mean2)*inv2*gg.z + bv.z);
    h4.w = (f16)((y[t][3]-mean2)*inv2*gg.w + bv.w);
    *(f16x4*)(out2 + ro + c0) = h4;
  }
}

__device__ __forceinline__ void ln_rows(
    const float* __restrict__ X,
    const float* __restrict__ g, const float* __restrict__ bb,
    f16* __restrict__ out, int gidx, int tid)
{
  const int lane = tid & 63;
  const size_t row = (size_t)gidx*4 + (tid>>6);
  const float* x = X + row*D_DIM;
  float4 v[3]; float s=0.f, ss=0.f;
  #pragma unroll
  for (int t=0;t<3;++t){
    v[t] = *(const float4*)(x + lane*4 + t*256);
    s  += v[t].x+v[t].y+v[t].z+v[t].w;
    ss += v[t].x*v[t].x+v[t].y*v[t].y+v[t].z*v[t].z+v[t].w*v[t].w;
  }
  #pragma unroll
  for (int m=1;m<64;m<<=1){ s += __shfl_xor(s,m); ss += __shfl_xor(ss,m); }
  float mean = s*(1.0f/768.0f);
  float inv  = rsqrtf(ss*(1.0f/768.0f) - mean*mean + 1e-5f);
  #pragma unroll
  for (int t=0;t<3;++t){
    int c0 = lane*4 + t*256;
    float4 gg = *(const float4*)(g + c0);
    float4 bv = *(const float4*)(bb + c0);
    f16x4 h4;
    h4.x = (f16)((v[t].x-mean)*inv*gg.x + bv.x);
    h4.y = (f16)((v[t].y-mean)*inv*gg.y + bv.y);
    h4.z = (f16)((v[t].z-mean)*inv*gg.z + bv.z);
    h4.w = (f16)((v[t].w-mean)*inv*gg.w + bv.w);
    *(f16x4*)(out + row*D_DIM + c0) = h4;
  }
}

__global__ __launch_bounds__(256) void mega_k(MegaArgs a)
{
  __shared__ __align__(16) char smraw[57600];
  cooperative_groups::grid_group grid = cooperative_groups::this_grid();
  const int tid = threadIdx.x;
  const int lane = tid & 63;
  const int w = tid >> 6;
  const int quad = lane>>4, l16 = lane&15;
  const int NBLK = gridDim.x;

  // ---- S0: dots (512 tiles) ----
  for (int tile = blockIdx.x; tile < 512; tile += NBLK){
    const int b = tile & 31, jt = tile >> 5;
    f16* qf = (f16*)smraw;               // 24576 B
    f16* ks = (f16*)(smraw + 24576);     // 32768 B
    float* rpart = (float*)(smraw + 57344);
    __syncthreads();
    #pragma unroll
    for (int c=0;c<6;++c){
      int p = c*256 + tid;
      int ki = p >> 6, qd = (p >> 4) & 3, rw = p & 15;
      f16x8 v = *(const f16x8*)(a.q + ((size_t)(b*NSLOT+rw))*D_DIM + ki*32 + qd*8);
      *(f16x8*)&qf[(size_t)p*8] = v;
    }
    const f16* gK = a.xn + ((size_t)(b*NTOK + jt*64 + (tid>>2)))*D_DIM + (tid&3)*8;
    LDS_AS f16* lK = (LDS_AS f16*)&ks[(size_t)tid*8];
    f32x4 acc = {};
    for (int it=0; it<3; ++it){
      #pragma unroll
      for (int p=0;p<8;++p)
        __builtin_amdgcn_global_load_lds((const GLOBAL_AS void*)(gK + it*256 + p*32),
                                         (LDS_AS void*)(lK + (size_t)p*2048), 16, 0, 0);
      __syncthreads();
      #pragma unroll
      for (int p=0;p<8;++p){
        f16x8 av = *(const f16x8*)&qf[(((size_t)(it*8+p)*4 + quad)*16 + l16)*8];
        f16x8 bf = *(const f16x8*)&ks[(size_t)p*2048 + (w*16+l16)*32 + quad*8];
        acc = __builtin_amdgcn_mfma_f32_16x16x32_f16(av, bf, acc, 0, 0, 0);
      }
      __syncthreads();
    }
    float v0 = acc[0]*SCALE_D, v1 = acc[1]*SCALE_D, v2 = acc[2]*SCALE_D, v3 = acc[3]*SCALE_D;
    float mx = fmaxf(fmaxf(v0,v1), fmaxf(v2,v3));
    mx = fmaxf(mx, __shfl_xor(mx, 16));
    mx = fmaxf(mx, __shfl_xor(mx, 32));
    float e0 = __expf(v0-mx), e1 = __expf(v1-mx), e2 = __expf(v2-mx), e3 = __expf(v3-mx);
    float s = e0+e1+e2+e3;
    s += __shfl_xor(s, 16);
    s += __shfl_xor(s, 32);
    float inv = 1.0f/s;
    float a0 = e0*inv + 1e-8f, a1 = e1*inv + 1e-8f, a2 = e2*inv + 1e-8f, a3 = e3*inv + 1e-8f;
    int jcol = jt*64 + w*16 + l16;
    int ibase = b*NSLOT + quad*4;
    a.attn[(size_t)(ibase+0)*NTOK + jcol] = (f16)a0;
    a.attn[(size_t)(ibase+1)*NTOK + jcol] = (f16)a1;
    a.attn[(size_t)(ibase+2)*NTOK + jcol] = (f16)a2;
    a.attn[(size_t)(ibase+3)*NTOK + jcol] = (f16)a3;
    float t0=a0, t1=a1, t2=a2, t3=a3;
    #pragma unroll
    for (int m=1;m<16;m<<=1){
      t0 += __shfl_xor(t0, m);
      t1 += __shfl_xor(t1, m);
      t2 += __shfl_xor(t2, m);
      t3 += __shfl_xor(t3, m);
    }
    if (l16 == 0){
      rpart[w*16 + quad*4+0] = t0;
      rpart[w*16 + quad*4+1] = t1;
      rpart[w*16 + quad*4+2] = t2;
      rpart[w*16 + quad*4+3] = t3;
    }
    __syncthreads();
    if (tid < 16){
      float ssum = rpart[0*16+tid] + rpart[1*16+tid] + rpart[2*16+tid] + rpart[3*16+tid];
      a.rsPart[(size_t)((b*16 + jt)<<4) + tid] = ssum;
    }
  }
  grid.sync();

  // ---- S1: attnv (384 tiles) ----
  for (int tile = blockIdx.x; tile < 384; tile += NBLK){
    const int b = tile & 31, d0 = (tile >> 5)*64;
    f16* Asl = (f16*)smraw;              // 8192 B
    f16* Bsl = (f16*)(smraw + 8192);     // 32768 B
    float* rsum = (float*)(smraw + 40960);
    __syncthreads();
    if (tid < 16){
      float s = 0.f;
      #pragma unroll
      for (int jt=0;jt<16;++jt) s += a.rsPart[(size_t)((b*16 + jt)<<4) + tid];
      rsum[tid] = s;
    }
    const int pa = tid>>6, ta = tid&63;
    const f16* gA = a.attn + ((size_t)(b*NSLOT + (ta>>2)))*NTOK + (ta&3)*8;
    const f16* gB = a.xnT + ((size_t)(d0 + (tid>>2)))*NTOT + b*NTOK + (tid&3)*8;
    LDS_AS f16* lB = (LDS_AS f16*)&Bsl[(size_t)tid*8];
    f32x4 acc = {};
    for (int it=0; it<4; ++it){
      #pragma unroll
      for (int q=0;q<2;++q){
        int pq = pa*2 + q;
        __builtin_amdgcn_global_load_lds((const GLOBAL_AS void*)(gA + it*256 + pq*32),
                                         (LDS_AS void*)((LDS_AS f16*)&Asl[(size_t)pq*512 + ta*8]), 16, 0, 0);
      }
      #pragma unroll
      for (int p=0;p<8;++p)
        __builtin_amdgcn_global_load_lds((const GLOBAL_AS void*)(gB + it*256 + p*32),
                                         (LDS_AS void*)(lB + (size_t)p*2048), 16, 0, 0);
      __syncthreads();
      #pragma unroll
      for (int p=0;p<8;++p){
        f16x8 av = *(const f16x8*)&Asl[(size_t)p*512 + l16*32 + quad*8];
        f16x8 bf = *(const f16x8*)&Bsl[(size_t)p*2048 + (w*16+l16)*32 + quad*8];
        acc = __builtin_amdgcn_mfma_f32_16x16x32_f16(av, bf, acc, 0, 0, 0);
      }
      __syncthreads();
    }
    int dcol = d0 + w*16 + l16;
    #pragma unroll
    for (int r=0;r<4;++r){
      int i = quad*4 + r;
      a.t[(size_t)(b*NSLOT + i)*D_DIM + dcol] = (f16)(acc[r] / rsum[i]);
    }
  }
  grid.sync();

  // ---- S2: upd = t @ Wv ----
  for (int tile = blockIdx.x; tile < 96; tile += NBLK)
    gemm_tile<0>(a.t, a.WvT, a.upd, 768, 768, (tile&7)*64, (tile>>3)*64, 0, 768, smraw, tid);
  grid.sync();

  // ---- S3: hbuf = LN(slots+upd); tmp = LN(hbuf, ln1) ----
  for (int g = blockIdx.x; g < 128; g += NBLK)
    lnln_rows<true>(a.slots, a.upd, a.nica_g, a.nica_b, a.ln1_g, a.ln1_b,
                    a.hbuf, a.tmp, g, tid);
  grid.sync();

  // ---- S4: qkv = tmp @ Wqkv ----
  for (int tile = blockIdx.x; tile < 192; tile += NBLK)
    gemm_tile<1>(a.tmp, a.WqkvT, a.qkv, 1536, 768, (tile&7)*64, (tile>>3)*64, 0, 768, smraw, tid);
  grid.sync();

  // ---- S5: encoder self-attention ----
  for (int tile = blockIdx.x; tile < 256; tile += NBLK){
    const int b = tile & 31, h = tile >> 5;
    float* qs = (float*)smraw;
    float* ks2 = (float*)(smraw + 4352);
    float* vs = (float*)(smraw + 8704);
    float* ps = (float*)(smraw + 13056);
    __syncthreads();
    {
      int i = tid>>4, dd=(tid&15)*4;
      size_t base = ((size_t)(b*NSLOT+i))*1536 + h*64 + dd;
      f16x4 uq = *(const f16x4*)(a.qkv + base);
      f16x4 uk = *(const f16x4*)(a.qkv + 512 + base);
      f16x4 uv = *(const f16x4*)(a.qkv + 1024 + base);
      float4 fq = { (float)uq.x, (float)uq.y, (float)uq.z, (float)uq.w };
      float4 fk = { (float)uk.x, (float)uk.y, (float)uk.z, (float)uk.w };
      float4 fv = { (float)uv.x, (float)uv.y, (float)uv.z, (float)uv.w };
      *(float4*)&qs[i*68+dd]=fq; *(float4*)&ks2[i*68+dd]=fk; *(float4*)&vs[i*68+dd]=fv;
    }
    __syncthreads();
    {
      int i = tid>>4, j = tid&15;
      float s=0.f;
      #pragma unroll 8
      for (int d=0; d<64; ++d) s += qs[i*68+d]*ks2[j*68+d];
      ps[i*20+j] = s*SCALE_H;
    }
    __syncthreads();
    if (tid < 16){
      int i = tid;
      float mx=-1e30f;
      #pragma unroll
      for (int j=0;j<16;++j) mx = fmaxf(mx, ps[i*20+j]);
      float sm=0.f;
      #pragma unroll
      for (int j=0;j<16;++j){ float e=__expf(ps[i*20+j]-mx); ps[i*20+j]=e; sm+=e; }
      float inv=1.0f/sm;
      #pragma unroll
      for (int j=0;j<16;++j) ps[i*20+j]*=inv;
    }
    __syncthreads();
    {
      int i = tid>>4, dq=(tid&15)*4;
      float a0=0,a1=0,a2=0,a3=0;
      #pragma unroll
      for (int j=0;j<16;++j){
        float p = ps[i*20+j];
        a0+=p*vs[j*68+dq+0]; a1+=p*vs[j*68+dq+1]; a2+=p*vs[j*68+dq+2]; a3+=p*vs[j*68+dq+3];
      }
      size_t base = ((size_t)(b*NSLOT+i))*HDIM + h*64 + dq;
      a.o[base+0]=(f16)a0; a.o[base+1]=(f16)a1; a.o[base+2]=(f16)a2; a.o[base+3]=(f16)a3;
    }
  }
  grid.sync();

  // ---- S6: hbuf += o @ Wo (split-2 atomic) ----
  for (int tile = blockIdx.x; tile < 192; tile += NBLK){
    int z = tile/96, r = tile%96;
    gemm_tile<2>(a.o, a.WoaT, a.hbuf, 768, 512, (r&7)*64, (r>>3)*64, z*256, 256, smraw, tid);
  }
  grid.sync();

  // ---- S7: tmp = LN(hbuf, ln2) ----
  for (int g = blockIdx.x; g < 128; g += NBLK)
    ln_rows(a.hbuf, a.ln2_g, a.ln2_b, a.tmp, g, tid);
  grid.sync();

  // ---- S8: act = glu(tmp @ W1) ----
  for (int tile = blockIdx.x; tile < 384; tile += NBLK){
    const int m0 = (tile&7)*64, n0 = (tile>>3)*64;
    f16* As = (f16*)smraw;
    f16* Bu = (f16*)(smraw + 16384);
    f16* Bg = (f16*)(smraw + 32768);
    const int wave = w;
    const int wm = (wave>>1)*32, wn = (wave&1)*32;
    const int sr = tid>>2, sc = (tid&3)*8;
    const f16* gA  = a.tmp + (size_t)(m0+sr)*768 + sc;
    const f16* gBu = a.W1T + (size_t)(n0+sr)*768 + sc;
    const f16* gBg = a.W1T + (size_t)(3072+n0+sr)*768 + sc;
    LDS_AS f16* lA  = (LDS_AS f16*)&As[(size_t)tid*8];
    LDS_AS f16* lBu = (LDS_AS f16*)&Bu[(size_t)tid*8];
    LDS_AS f16* lBg = (LDS_AS f16*)&Bg[(size_t)tid*8];
    const f16* fA0 = &As[(wm + l16)*32 + quad*8];
    const f16* fU0 = &Bu[(wn + l16)*32 + quad*8];
    const f16* fG0 = &Bg[(wn + l16)*32 + quad*8];
    f32x4 accU[2][2] = {};
    f32x4 accG[2][2] = {};
    for (int k0 = 0; k0 < 768; k0 += 128){
      #pragma unroll
      for (int p=0;p<4;++p){
        __builtin_amdgcn_global_load_lds((const GLOBAL_AS void*)(gA  + k0 + p*32),
                                         (LDS_AS void*)(lA  + (size_t)p*2048), 16, 0, 0);
        __builtin_amdgcn_global_load_lds((const GLOBAL_AS void*)(gBu + k0 + p*32),
                                         (LDS_AS void*)(lBu + (size_t)p*2048), 16, 0, 0);
        __builtin_amdgcn_global_load_lds((const GLOBAL_AS void*)(gBg + k0 + p*32),
                                         (LDS_AS void*)(lBg + (size_t)p*2048), 16, 0, 0);
      }
      __syncthreads();
      #pragma unroll
      for (int p=0;p<4;++p){
        f16x8 a0 = *(const f16x8*)(fA0 + p*2048);
        f16x8 a1 = *(const f16x8*)(fA0 + p*2048 + 16*32);
        f16x8 u0 = *(const f16x8*)(fU0 + p*2048);
        f16x8 u1 = *(const f16x8*)(fU0 + p*2048 + 16*32);
        f16x8 g0 = *(const f16x8*)(fG0 + p*2048);
        f16x8 g1 = *(const f16x8*)(fG0 + p*2048 + 16*32);
        accU[0][0] = __builtin_amdgcn_mfma_f32_16x16x32_f16(a0,u0,accU[0][0],0,0,0);
        accU[0][1] = __builtin_amdgcn_mfma_f32_16x16x32_f16(a0,u1,accU[0][1],0,0,0);
        accU[1][0] = __builtin_amdgcn_mfma_f32_16x16x32_f16(a1,u0,accU[1][0],0,0,0);
        accU[1][1] = __builtin_amdgcn_mfma_f32_16x16x32_f16(a1,u1,accU[1][1],0,0,0);
        accG[0][0] = __builtin_amdgcn_mfma_f32_16x16x32_f16(a0,g0,accG[0][0],0,0,0);
        accG[0][1] = __builtin_amdgcn_mfma_f32_16x16x32_f16(a0,g1,accG[0][1],0,0,0);
        accG[1][0] = __builtin_amdgcn_mfma_f32_16x16x32_f16(a1,g0,accG[1][0],0,0,0);
        accG[1][1] = __builtin_amdgcn_mfma_f32_16x16x32_f16(a1,g1,accG[1][1],0,0,0);
      }
      __syncthreads();
    }
    #pragma unroll
    for (int mt=0;mt<2;++mt){
      #pragma unroll
      for (int nt=0;nt<2;++nt){
        int gm = m0 + wm + mt*16 + quad*4;
        int gn = n0 + wn + nt*16 + l16;
        #pragma unroll
        for (int r=0;r<4;++r){
          float u = accU[mt][nt][r];
          float g = accG[mt][nt][r];
          float sg = g / (1.0f + __expf(-g));
          a.act[(size_t)(gm+r)*INNER + gn] = (f16)(u*sg);
        }
      }
    }
  }
  grid.sync();

  // ---- S9: hbuf += act @ W2 (split-4 atomic) ----
  for (int tile = blockIdx.x; tile < 384; tile += NBLK){
    int z = tile/96, r = tile%96;
    gemm_tile<2>(a.act, a.W2T, a.hbuf, 768, 3072, (r&7)*64, (r>>3)*64, z*768, 768, smraw, tid);
  }
  grid.sync();

  // ---- S10: out1 = LN(hbuf,lnf); tmp2 = LN(out1, ns) ----
  for (int g = blockIdx.x; g < 128; g += NBLK)
    lnln_rows<false>(a.hbuf, nullptr, a.lnf_g, a.lnf_b, a.ns_g, a.ns_b,
                     a.out1, a.tmp2, g, tid);

  // ---- S11: qnext = tmp2 @ BtQK ----
  if (a.doQnext){
    grid.sync();
    for (int tile = blockIdx.x; tile < 96; tile += NBLK)
      gemm_tile<1>(a.tmp2, a.BtQK, a.qnext, 768, 768, (tile&7)*64, (tile>>3)*64, 0, 768, smraw, tid);
  }
}

extern "C" void kernel_launch(void* const* d_in, const int* in_sizes, int n_in,
                              void* d_out, int out_size, void* d_ws, size_t ws_size,
                              hipStream_t stream) {
  const float* x        = (const float*)d_in[0];
  const float* noise    = (const float*)d_in[1];
  const float* init_mu  = (const float*)d_in[2];
  const float* init_ls  = (const float*)d_in[3];
  const float* Wk       = (const float*)d_in[4];
  const float* Wv       = (const float*)d_in[5];
  const float* Wq       = (const float*)d_in[6];
  const float* ni_g     = (const float*)d_in[7];
  const float* ni_b     = (const float*)d_in[8];
  const float* ns_g     = (const float*)d_in[9];
  const float* ns_b     = (const float*)d_in[10];
  const float* nica_g   = (const float*)d_in[11];
  const float* nica_b   = (const float*)d_in[12];
  const float* ln1_g    = (const float*)d_in[13];
  const float* ln1_b    = (const float*)d_in[14];
  const float* Wq_a     = (const float*)d_in[15];
  const float* Wk_a     = (const float*)d_in[16];
  const float* Wv_a     = (const float*)d_in[17];
  const float* Wo_a     = (const float*)d_in[18];
  const float* ln2_g    = (const float*)d_in[19];
  const float* ln2_b    = (const float*)d_in[20];
  const float* W1       = (const float*)d_in[21];
  const float* W2       = (const float*)d_in[22];
  const float* lnf_g    = (const float*)d_in[23];
  const float* lnf_b    = (const float*)d_in[24];

  char* w = (char*)d_ws;
  size_t off = 0;
  auto alloc = [&](size_t bytes)->char*{
    char* p = w + off; off += (bytes + 255) & ~(size_t)255; return p;
  };
  f16* xn_h  = (f16*)alloc((size_t)NTOT*D_DIM*2);
  f16* xnT_h = (f16*)alloc((size_t)D_DIM*NTOT*2);
  f16* Wkf   = (f16*)alloc((size_t)768*768*2);
  f16* Wqf   = (f16*)alloc((size_t)768*768*2);
  f16* BtQK  = (f16*)alloc((size_t)768*768*2);
  f16* WvT   = (f16*)alloc((size_t)768*768*2);
  f16* WqkvT = (f16*)alloc((size_t)1536*768*2);
  f16* WoaT  = (f16*)alloc((size_t)768*512*2);
  f16* W1T   = (f16*)alloc((size_t)6144*768*2);
  f16* W2T   = (f16*)alloc((size_t)768*3072*2);
  float* slots = (float*)alloc(512*768*4);
  float* hbuf  = (float*)alloc(512*768*4);
  float* upd   = (float*)alloc(512*768*4);
  f16* tmp_h  = (f16*)alloc(512*768*2);
  f16* tmp2_h = (f16*)alloc(512*768*2);
  f16* q_h    = (f16*)alloc(512*768*2);
  f16* t_h    = (f16*)alloc(512*768*2);
  f16* qkv_h  = (f16*)alloc((size_t)512*1536*2);
  f16* o_h    = (f16*)alloc(512*512*2);
  f16* act_h  = (f16*)alloc((size_t)512*3072*2);
  f16* attn_h = (f16*)alloc((size_t)NB*NSLOT*NTOK*2);
  float* rsPart = (float*)alloc((size_t)32*16*16*4);

  prep_k<<<10176, 256, 0, stream>>>(Wv, Wq_a, Wk_a, Wv_a, Wo_a, W1, W2, Wk, Wq,
                                    WvT, WqkvT, WoaT, W1T, W2T, Wkf, Wqf);
  mgemm64_k<1><<<dim3(12, 12, 1), 256, 0, stream>>>(Wkf, Wqf, BtQK, 768, 768, 768, 768);
  lnw_k<<<NTOT/4, 256, 0, stream>>>(x, ni_g, ni_b, xn_h);
  transp_k<<<dim3(NTOT/64, D_DIM/64), 256, 0, stream>>>(xn_h, xnT_h, NTOT, D_DIM);
  slotsinit_k<<<128, 256, 0, stream>>>(noise, init_mu, init_ls, ns_g, ns_b,
                                       slots, tmp2_h);
  // q_eff for iteration 0
  mgemm64_k<1><<<dim3(8, 12, 1), 256, 0, stream>>>(tmp2_h, BtQK, q_h, 512, 768, 768, 768);

  // cooperative capacity check (host query, capture-safe)
  int occ = 0;
  bool coop = (hipOccupancyMaxActiveBlocksPerMultiprocessor(&occ, mega_k, 256, 0) == hipSuccess)
              && (occ >= 1);
  int nblk = 0;
  if (coop){
    nblk = occ * 256;
    if (nblk > 512) nblk = 512;
  }

  for (int it=0; it<4; ++it){
    bool ran_coop = false;
    if (coop){
      MegaArgs ma;
      ma.q = q_h; ma.xn = xn_h; ma.xnT = xnT_h;
      ma.attn = attn_h; ma.rsPart = rsPart; ma.t = t_h;
      ma.WvT = WvT; ma.upd = upd;
      ma.slots = slots; ma.hbuf = hbuf;
      ma.tmp = tmp_h; ma.tmp2 = tmp2_h;
      ma.WqkvT = WqkvT; ma.qkv = qkv_h; ma.o = o_h;
      ma.WoaT = WoaT; ma.W1T = W1T; ma.act = act_h; ma.W2T = W2T;
      ma.BtQK = BtQK; ma.qnext = q_h;
      ma.out1 = (it==3) ? (float*)d_out : slots;
      ma.nica_g = nica_g; ma.nica_b = nica_b;
      ma.ln1_g = ln1_g;   ma.ln1_b = ln1_b;
      ma.ln2_g = ln2_g;   ma.ln2_b = ln2_b;
      ma.lnf_g = lnf_g;   ma.lnf_b = lnf_b;
      ma.ns_g = ns_g;     ma.ns_b = ns_b;
      ma.doQnext = (it<3) ? 1 : 0;
      void* kp[] = { &ma };
      hipError_t err = hipLaunchCooperativeKernel((const void*)mega_k,
                                                  dim3(nblk), dim3(256), kp, 0, stream);
      if (err == hipSuccess) ran_coop = true;
      else coop = false;   // permanent fallback
    }
    if (!ran_coop){
      // R5 fallback path. Recompute q_eff from tmp2 (valid from prior iter, any path).
      if (it > 0)
        mgemm64_k<1><<<dim3(8, 12, 1), 256, 0, stream>>>(tmp2_h, BtQK, q_h, 512, 768, 768, 768);
      dots_k<<<dim3(NB, 16), 256, 0, stream>>>(q_h, xn_h, attn_h, rsPart);
      attnv_k<<<dim3(NB, 12), 256, 0, stream>>>(attn_h, rsPart, xnT_h, t_h);
      mgemm64_k<0><<<dim3(8, 12, 1), 256, 0, stream>>>(t_h, WvT, upd, 512, 768, 768, 768);
      lnlnw_k<true><<<128, 256, 0, stream>>>(slots, upd, nica_g, nica_b, ln1_g, ln1_b,
                                             hbuf, tmp_h);
      mgemm64_k<1><<<dim3(8, 24, 1), 256, 0, stream>>>(tmp_h, WqkvT, qkv_h, 512, 1536, 768, 768);
      encattn_k<<<dim3(NB, 8), 256, 0, stream>>>(qkv_h, qkv_h + 512, qkv_h + 1024, 1536, o_h);
      mgemm64_k<2><<<dim3(8, 12, 2), 256, 0, stream>>>(o_h, WoaT, hbuf, 512, 768, 512, 256);
      lnw_k<<<128, 256, 0, stream>>>(hbuf, ln2_g, ln2_b, tmp_h);
      w1glu_k<<<dim3(8, 48), 256, 0, stream>>>(tmp_h, W1T, act_h, 512);
      mgemm64_k<2><<<dim3(8, 12, 4), 256, 0, stream>>>(act_h, W2T, hbuf, 512, 768, 3072, 768);
      float* out1 = (it==3) ? (float*)d_out : slots;
      lnlnw_k<false><<<128, 256, 0, stream>>>(hbuf, nullptr, lnf_g, lnf_b, ns_g, ns_b,
                                              out1, tmp2_h);
    }
  }

  attnout_k<<<NB*NTOK*NSLOT/256, 256, 0, stream>>>(attn_h, rsPart, (float*)d_out + 512*768);
}

// Round 9
// 624.570 us; speedup vs baseline: 3.1188x; 3.1188x over previous
//
#include <hip/hip_runtime.h>
#include <hip/hip_bf16.h>
#include <stdint.h>

typedef _Float16 f16;
typedef __attribute__((ext_vector_type(8))) _Float16 f16x8;
typedef __attribute__((ext_vector_type(4))) _Float16 f16x4;
typedef __attribute__((ext_vector_type(4))) float f32x4;

#define GLOBAL_AS __attribute__((address_space(1)))
#define LDS_AS __attribute__((address_space(3)))

#define D_DIM 768
#define NTOK 1024
#define NSLOT 16
#define NB 32
#define NTOT (NB*NTOK)   // 32768
#define HDIM 512
#define INNER 3072
#define SCALE_D 0.03608439182435161f   // 768^-0.5
#define SCALE_H 0.125f                 // 64^-0.5

// ---------- MFMA GEMM 64x64, BK=256 (8 panels, one drain per 256-K step), split-K ----------
// OUT: 0 = f32 store, 1 = f16 store, 2 = f32 atomicAdd.  Kc % 256 == 0.
template<int OUT>
__global__ __launch_bounds__(256) void mgemm64_k(
    const f16* __restrict__ A, const f16* __restrict__ Bt,
    void* __restrict__ Cout, int M, int N, int K, int Kc)
{
  __shared__ __align__(16) f16 As[64*256];
  __shared__ __align__(16) f16 Bs[64*256];
  const int tid = threadIdx.x;
  const int lane = tid & 63;
  const int wave = tid >> 6;
  const int m0 = blockIdx.x*64, n0 = blockIdx.y*64;
  const int kbeg = blockIdx.z * Kc;
  const int wm = (wave>>1)*32, wn = (wave&1)*32;
  const int quad = lane>>4, l16 = lane&15;

  const int sr = tid>>2;
  const int sc = (tid&3)*8;
  const f16* gA = A  + (size_t)(m0+sr)*K + kbeg + sc;
  const f16* gB = Bt + (size_t)(n0+sr)*K + kbeg + sc;
  LDS_AS f16* lA = (LDS_AS f16*)&As[(size_t)tid*8];
  LDS_AS f16* lB = (LDS_AS f16*)&Bs[(size_t)tid*8];

  const f16* fA0 = &As[(wm + l16)*32 + quad*8];
  const f16* fB0 = &Bs[(wn + l16)*32 + quad*8];

  f32x4 acc[2][2] = {};

  for (int k0 = 0; k0 < Kc; k0 += 256){
    #pragma unroll
    for (int p=0;p<8;++p){
      __builtin_amdgcn_global_load_lds((const GLOBAL_AS void*)(gA + k0 + p*32),
                                       (LDS_AS void*)(lA + (size_t)p*2048), 16, 0, 0);
      __builtin_amdgcn_global_load_lds((const GLOBAL_AS void*)(gB + k0 + p*32),
                                       (LDS_AS void*)(lB + (size_t)p*2048), 16, 0, 0);
    }
    __syncthreads();
    #pragma unroll
    for (int p=0;p<8;++p){
      f16x8 a0 = *(const f16x8*)(fA0 + p*2048);
      f16x8 a1 = *(const f16x8*)(fA0 + p*2048 + 16*32);
      f16x8 b0 = *(const f16x8*)(fB0 + p*2048);
      f16x8 b1 = *(const f16x8*)(fB0 + p*2048 + 16*32);
      acc[0][0] = __builtin_amdgcn_mfma_f32_16x16x32_f16(a0,b0,acc[0][0],0,0,0);
      acc[0][1] = __builtin_amdgcn_mfma_f32_16x16x32_f16(a0,b1,acc[0][1],0,0,0);
      acc[1][0] = __builtin_amdgcn_mfma_f32_16x16x32_f16(a1,b0,acc[1][0],0,0,0);
      acc[1][1] = __builtin_amdgcn_mfma_f32_16x16x32_f16(a1,b1,acc[1][1],0,0,0);
    }
    __syncthreads();
  }
  #pragma unroll
  for (int mt=0;mt<2;++mt){
    #pragma unroll
    for (int nt=0;nt<2;++nt){
      int gm = m0 + wm + mt*16 + quad*4;
      int gn = n0 + wn + nt*16 + l16;
      #pragma unroll
      for (int r=0;r<4;++r){
        float c = acc[mt][nt][r];
        size_t idx = (size_t)(gm+r)*N + gn;
        if (OUT==0)      ((float*)Cout)[idx] = c;
        else if (OUT==1) ((f16*)Cout)[idx] = (f16)c;
        else             atomicAdd(&((float*)Cout)[idx], c);
      }
    }
  }
}

// ---------- W1 + GLU fused (BK=128: 3 LDS buffers, keep 3 blocks/CU) ----------
__global__ __launch_bounds__(256) void w1glu_k(
    const f16* __restrict__ A, const f16* __restrict__ W1T,
    f16* __restrict__ act, int M)
{
  __shared__ __align__(16) f16 As[64*128];
  __shared__ __align__(16) f16 Bu[64*128];
  __shared__ __align__(16) f16 Bg[64*128];
  const int K = 768;
  const int tid = threadIdx.x;
  const int lane = tid & 63;
  const int wave = tid >> 6;
  const int m0 = blockIdx.x*64, n0 = blockIdx.y*64;
  const int wm = (wave>>1)*32, wn = (wave&1)*32;
  const int quad = lane>>4, l16 = lane&15;

  const int sr = tid>>2;
  const int sc = (tid&3)*8;
  const f16* gA  = A   + (size_t)(m0+sr)*K + sc;
  const f16* gBu = W1T + (size_t)(n0+sr)*K + sc;
  const f16* gBg = W1T + (size_t)(3072+n0+sr)*K + sc;
  LDS_AS f16* lA  = (LDS_AS f16*)&As[(size_t)tid*8];
  LDS_AS f16* lBu = (LDS_AS f16*)&Bu[(size_t)tid*8];
  LDS_AS f16* lBg = (LDS_AS f16*)&Bg[(size_t)tid*8];

  const f16* fA0 = &As[(wm + l16)*32 + quad*8];
  const f16* fU0 = &Bu[(wn + l16)*32 + quad*8];
  const f16* fG0 = &Bg[(wn + l16)*32 + quad*8];

  f32x4 accU[2][2] = {};
  f32x4 accG[2][2] = {};

  for (int k0 = 0; k0 < K; k0 += 128){
    #pragma unroll
    for (int p=0;p<4;++p){
      __builtin_amdgcn_global_load_lds((const GLOBAL_AS void*)(gA  + k0 + p*32),
                                       (LDS_AS void*)(lA  + (size_t)p*2048), 16, 0, 0);
      __builtin_amdgcn_global_load_lds((const GLOBAL_AS void*)(gBu + k0 + p*32),
                                       (LDS_AS void*)(lBu + (size_t)p*2048), 16, 0, 0);
      __builtin_amdgcn_global_load_lds((const GLOBAL_AS void*)(gBg + k0 + p*32),
                                       (LDS_AS void*)(lBg + (size_t)p*2048), 16, 0, 0);
    }
    __syncthreads();
    #pragma unroll
    for (int p=0;p<4;++p){
      f16x8 a0 = *(const f16x8*)(fA0 + p*2048);
      f16x8 a1 = *(const f16x8*)(fA0 + p*2048 + 16*32);
      f16x8 u0 = *(const f16x8*)(fU0 + p*2048);
      f16x8 u1 = *(const f16x8*)(fU0 + p*2048 + 16*32);
      f16x8 g0 = *(const f16x8*)(fG0 + p*2048);
      f16x8 g1 = *(const f16x8*)(fG0 + p*2048 + 16*32);
      accU[0][0] = __builtin_amdgcn_mfma_f32_16x16x32_f16(a0,u0,accU[0][0],0,0,0);
      accU[0][1] = __builtin_amdgcn_mfma_f32_16x16x32_f16(a0,u1,accU[0][1],0,0,0);
      accU[1][0] = __builtin_amdgcn_mfma_f32_16x16x32_f16(a1,u0,accU[1][0],0,0,0);
      accU[1][1] = __builtin_amdgcn_mfma_f32_16x16x32_f16(a1,u1,accU[1][1],0,0,0);
      accG[0][0] = __builtin_amdgcn_mfma_f32_16x16x32_f16(a0,g0,accG[0][0],0,0,0);
      accG[0][1] = __builtin_amdgcn_mfma_f32_16x16x32_f16(a0,g1,accG[0][1],0,0,0);
      accG[1][0] = __builtin_amdgcn_mfma_f32_16x16x32_f16(a1,g0,accG[1][0],0,0,0);
      accG[1][1] = __builtin_amdgcn_mfma_f32_16x16x32_f16(a1,g1,accG[1][1],0,0,0);
    }
    __syncthreads();
  }
  #pragma unroll
  for (int mt=0;mt<2;++mt){
    #pragma unroll
    for (int nt=0;nt<2;++nt){
      int gm = m0 + wm + mt*16 + quad*4;
      int gn = n0 + wn + nt*16 + l16;
      #pragma unroll
      for (int r=0;r<4;++r){
        float u = accU[mt][nt][r];
        float g = accG[mt][nt][r];
        float sg = g / (1.0f + __expf(-g));
        act[(size_t)(gm+r)*INNER + gn] = (f16)(u*sg);
      }
    }
  }
}

// ---------- MFMA dots (q_eff @ xn^T) + inverted softmax + EPS + partial rowsum ----------
// BK=256: 3 drains instead of 6.
__global__ __launch_bounds__(256) void dots_k(
    const f16* __restrict__ Q,    // [32,16,768] q_eff
    const f16* __restrict__ Xn,   // [32768,768]
    f16* __restrict__ attn,       // [32,16,1024] f16
    float* __restrict__ rsPart)   // [32][16 jt][16 i]
{
  __shared__ __align__(16) f16 qf[16*768];    // A-frag layout, 24 KB
  __shared__ __align__(16) f16 ks[64*256];    // 8 panels [64][32], 32 KB
  __shared__ float rpart[4][16];
  const int b = blockIdx.x, jt = blockIdx.y;
  const int tid = threadIdx.x;
  const int lane = tid & 63;
  const int w = tid >> 6;
  const int quad = lane>>4, l16 = lane&15;

  #pragma unroll
  for (int c=0;c<6;++c){
    int p = c*256 + tid;
    int ki = p >> 6, qd = (p >> 4) & 3, rw = p & 15;
    f16x8 v = *(const f16x8*)(Q + ((size_t)(b*NSLOT+rw))*D_DIM + ki*32 + qd*8);
    *(f16x8*)&qf[(size_t)p*8] = v;
  }

  const f16* gK = Xn + ((size_t)(b*NTOK + jt*64 + (tid>>2)))*D_DIM + (tid&3)*8;
  LDS_AS f16* lK = (LDS_AS f16*)&ks[(size_t)tid*8];

  f32x4 acc = {};
  for (int it=0; it<3; ++it){
    #pragma unroll
    for (int p=0;p<8;++p)
      __builtin_amdgcn_global_load_lds((const GLOBAL_AS void*)(gK + it*256 + p*32),
                                       (LDS_AS void*)(lK + (size_t)p*2048), 16, 0, 0);
    __syncthreads();
    #pragma unroll
    for (int p=0;p<8;++p){
      f16x8 a  = *(const f16x8*)&qf[(((size_t)(it*8+p)*4 + quad)*16 + l16)*8];
      f16x8 bf = *(const f16x8*)&ks[(size_t)p*2048 + (w*16+l16)*32 + quad*8];
      acc = __builtin_amdgcn_mfma_f32_16x16x32_f16(a, bf, acc, 0, 0, 0);
    }
    __syncthreads();
  }

  float v0 = acc[0]*SCALE_D, v1 = acc[1]*SCALE_D, v2 = acc[2]*SCALE_D, v3 = acc[3]*SCALE_D;
  float mx = fmaxf(fmaxf(v0,v1), fmaxf(v2,v3));
  mx = fmaxf(mx, __shfl_xor(mx, 16));
  mx = fmaxf(mx, __shfl_xor(mx, 32));
  float e0 = __expf(v0-mx), e1 = __expf(v1-mx), e2 = __expf(v2-mx), e3 = __expf(v3-mx);
  float s = e0+e1+e2+e3;
  s += __shfl_xor(s, 16);
  s += __shfl_xor(s, 32);
  float inv = 1.0f/s;
  float a0 = e0*inv + 1e-8f, a1 = e1*inv + 1e-8f, a2 = e2*inv + 1e-8f, a3 = e3*inv + 1e-8f;

  int jcol = jt*64 + w*16 + l16;
  int ibase = b*NSLOT + quad*4;
  attn[(size_t)(ibase+0)*NTOK + jcol] = (f16)a0;
  attn[(size_t)(ibase+1)*NTOK + jcol] = (f16)a1;
  attn[(size_t)(ibase+2)*NTOK + jcol] = (f16)a2;
  attn[(size_t)(ibase+3)*NTOK + jcol] = (f16)a3;

  float t0=a0, t1=a1, t2=a2, t3=a3;
  #pragma unroll
  for (int m=1;m<16;m<<=1){
    t0 += __shfl_xor(t0, m);
    t1 += __shfl_xor(t1, m);
    t2 += __shfl_xor(t2, m);
    t3 += __shfl_xor(t3, m);
  }
  if (l16 == 0){
    rpart[w][quad*4+0] = t0;
    rpart[w][quad*4+1] = t1;
    rpart[w][quad*4+2] = t2;
    rpart[w][quad*4+3] = t3;
  }
  __syncthreads();
  if (tid < 16){
    float ss = rpart[0][tid] + rpart[1][tid] + rpart[2][tid] + rpart[3][tid];
    rsPart[(size_t)((b*16 + jt)<<4) + tid] = ss;
  }
}

// ---------- t = (attn @ xn) / rowsum via MFMA on xnT; BK=256: 4 drains ----------
__global__ __launch_bounds__(256) void attnv_k(
    const f16* __restrict__ attn,   // [32,16,1024] f16
    const float* __restrict__ rsPart,
    const f16* __restrict__ XnT,    // [768, 32768]
    f16* __restrict__ t_out)        // [32,16,768] f16
{
  __shared__ __align__(16) f16 Asl[16*256];
  __shared__ __align__(16) f16 Bsl[64*256];
  __shared__ float rsum[16];
  const int b = blockIdx.x, d0 = blockIdx.y*64;
  const int tid = threadIdx.x;
  const int lane = tid & 63;
  const int w = tid >> 6;
  const int quad = lane>>4, l16 = lane&15;

  if (tid < 16){
    float s = 0.f;
    #pragma unroll
    for (int jt=0;jt<16;++jt) s += rsPart[(size_t)((b*16 + jt)<<4) + tid];
    rsum[tid] = s;
  }

  const int pa = tid>>6, ta = tid&63;
  const f16* gA = attn + ((size_t)(b*NSLOT + (ta>>2)))*NTOK + (ta&3)*8;
  const f16* gB = XnT + ((size_t)(d0 + (tid>>2)))*NTOT + b*NTOK + (tid&3)*8;
  LDS_AS f16* lB = (LDS_AS f16*)&Bsl[(size_t)tid*8];

  f32x4 acc = {};
  for (int it=0; it<4; ++it){
    #pragma unroll
    for (int q=0;q<2;++q){
      int pq = pa*2 + q;
      __builtin_amdgcn_global_load_lds((const GLOBAL_AS void*)(gA + it*256 + pq*32),
                                       (LDS_AS void*)((LDS_AS f16*)&Asl[(size_t)pq*512 + ta*8]), 16, 0, 0);
    }
    #pragma unroll
    for (int p=0;p<8;++p)
      __builtin_amdgcn_global_load_lds((const GLOBAL_AS void*)(gB + it*256 + p*32),
                                       (LDS_AS void*)(lB + (size_t)p*2048), 16, 0, 0);
    __syncthreads();
    #pragma unroll
    for (int p=0;p<8;++p){
      f16x8 a  = *(const f16x8*)&Asl[(size_t)p*512 + l16*32 + quad*8];
      f16x8 bf = *(const f16x8*)&Bsl[(size_t)p*2048 + (w*16+l16)*32 + quad*8];
      acc = __builtin_amdgcn_mfma_f32_16x16x32_f16(a, bf, acc, 0, 0, 0);
    }
    __syncthreads();
  }
  int dcol = d0 + w*16 + l16;
  #pragma unroll
  for (int r=0;r<4;++r){
    int i = quad*4 + r;
    t_out[(size_t)(b*NSLOT + i)*D_DIM + dcol] = (f16)(acc[r] / rsum[i]);
  }
}

// ---------- wave-per-row LN (4 rows/block), f16 out ----------
__global__ __launch_bounds__(256) void lnw_k(
    const float* __restrict__ X,
    const float* __restrict__ g, const float* __restrict__ bb,
    f16* __restrict__ out)
{
  const int lane = threadIdx.x & 63;
  const size_t row = (size_t)blockIdx.x*4 + (threadIdx.x>>6);
  const float* x = X + row*D_DIM;
  float4 v[3]; float s=0.f, ss=0.f;
  #pragma unroll
  for (int t=0;t<3;++t){
    v[t] = *(const float4*)(x + lane*4 + t*256);
    s  += v[t].x+v[t].y+v[t].z+v[t].w;
    ss += v[t].x*v[t].x+v[t].y*v[t].y+v[t].z*v[t].z+v[t].w*v[t].w;
  }
  #pragma unroll
  for (int m=1;m<64;m<<=1){ s += __shfl_xor(s,m); ss += __shfl_xor(ss,m); }
  float mean = s*(1.0f/768.0f);
  float inv  = rsqrtf(ss*(1.0f/768.0f) - mean*mean + 1e-5f);
  #pragma unroll
  for (int t=0;t<3;++t){
    int c0 = lane*4 + t*256;
    float4 gg = *(const float4*)(g + c0);
    float4 bv = *(const float4*)(bb + c0);
    f16x4 h4;
    h4.x = (f16)((v[t].x-mean)*inv*gg.x + bv.x);
    h4.y = (f16)((v[t].y-mean)*inv*gg.y + bv.y);
    h4.z = (f16)((v[t].z-mean)*inv*gg.z + bv.z);
    h4.w = (f16)((v[t].w-mean)*inv*gg.w + bv.w);
    *(f16x4*)(out + row*D_DIM + c0) = h4;
  }
}

// ---------- wave-per-row double LN: out1=LN(X[+X2],g1,b1) f32, out2=LN(out1,g2,b2) f16 ----------
template<bool ADD>
__global__ __launch_bounds__(256) void lnlnw_k(
    const float* __restrict__ X, const float* __restrict__ X2,
    const float* __restrict__ g1, const float* __restrict__ b1,
    const float* __restrict__ g2, const float* __restrict__ b2,
    float* __restrict__ out1, f16* __restrict__ out2)
{
  const int lane = threadIdx.x & 63;
  const size_t row = (size_t)blockIdx.x*4 + (threadIdx.x>>6);
  const float* x = X + row*D_DIM;
  const float* x2 = X2 + row*D_DIM;
  float4 v[3]; float s=0.f, ss=0.f;
  #pragma unroll
  for (int t=0;t<3;++t){
    int c0 = lane*4 + t*256;
    float4 a = *(const float4*)(x + c0);
    if (ADD){
      float4 b = *(const float4*)(x2 + c0);
      a.x+=b.x; a.y+=b.y; a.z+=b.z; a.w+=b.w;
    }
    v[t]=a;
    s  += v[t].x+v[t].y+v[t].z+v[t].w;
    ss += v[t].x*v[t].x+v[t].y*v[t].y+v[t].z*v[t].z+v[t].w*v[t].w;
  }
  #pragma unroll
  for (int m=1;m<64;m<<=1){ s += __shfl_xor(s,m); ss += __shfl_xor(ss,m); }
  float mean = s*(1.0f/768.0f);
  float inv  = rsqrtf(ss*(1.0f/768.0f) - mean*mean + 1e-5f);
  float y[3][4]; float s2=0.f, ss2=0.f;
  #pragma unroll
  for (int t=0;t<3;++t){
    int c0 = lane*4 + t*256;
    float4 gg = *(const float4*)(g1 + c0);
    float4 bv = *(const float4*)(b1 + c0);
    y[t][0] = (v[t].x-mean)*inv*gg.x + bv.x;
    y[t][1] = (v[t].y-mean)*inv*gg.y + bv.y;
    y[t][2] = (v[t].z-mean)*inv*gg.z + bv.z;
    y[t][3] = (v[t].w-mean)*inv*gg.w + bv.w;
    float4 o = { y[t][0], y[t][1], y[t][2], y[t][3] };
    *(float4*)(out1 + row*D_DIM + c0) = o;
    s2  += y[t][0]+y[t][1]+y[t][2]+y[t][3];
    ss2 += y[t][0]*y[t][0]+y[t][1]*y[t][1]+y[t][2]*y[t][2]+y[t][3]*y[t][3];
  }
  #pragma unroll
  for (int m=1;m<64;m<<=1){ s2 += __shfl_xor(s2,m); ss2 += __shfl_xor(ss2,m); }
  float mean2 = s2*(1.0f/768.0f);
  float inv2  = rsqrtf(ss2*(1.0f/768.0f) - mean2*mean2 + 1e-5f);
  #pragma unroll
  for (int t=0;t<3;++t){
    int c0 = lane*4 + t*256;
    float4 gg = *(const float4*)(g2 + c0);
    float4 bv = *(const float4*)(b2 + c0);
    f16x4 h4;
    h4.x = (f16)((y[t][0]-mean2)*inv2*gg.x + bv.x);
    h4.y = (f16)((y[t][1]-mean2)*inv2*gg.y + bv.y);
    h4.z = (f16)((y[t][2]-mean2)*inv2*gg.z + bv.z);
    h4.w = (f16)((y[t][3]-mean2)*inv2*gg.w + bv.w);
    *(f16x4*)(out2 + row*D_DIM + c0) = h4;
  }
}

// ---------- slots init + LN(ns) fused ----------
__global__ __launch_bounds__(256) void slotsinit_k(
    const float* __restrict__ noise, const float* __restrict__ mu,
    const float* __restrict__ ls,
    const float* __restrict__ nsg, const float* __restrict__ nsb,
    float* __restrict__ slots, f16* __restrict__ tmp2)
{
  const int lane = threadIdx.x & 63;
  const size_t row = (size_t)blockIdx.x*4 + (threadIdx.x>>6);
  float4 v[3]; float s=0.f, ss=0.f;
  #pragma unroll
  for (int t=0;t<3;++t){
    int c0 = lane*4 + t*256;
    float4 nz = *(const float4*)(noise + row*D_DIM + c0);
    float4 m4 = *(const float4*)(mu + c0);
    float4 l4 = *(const float4*)(ls + c0);
    v[t].x = m4.x + __expf(l4.x)*nz.x;
    v[t].y = m4.y + __expf(l4.y)*nz.y;
    v[t].z = m4.z + __expf(l4.z)*nz.z;
    v[t].w = m4.w + __expf(l4.w)*nz.w;
    *(float4*)(slots + row*D_DIM + c0) = v[t];
    s  += v[t].x+v[t].y+v[t].z+v[t].w;
    ss += v[t].x*v[t].x+v[t].y*v[t].y+v[t].z*v[t].z+v[t].w*v[t].w;
  }
  #pragma unroll
  for (int m=1;m<64;m<<=1){ s += __shfl_xor(s,m); ss += __shfl_xor(ss,m); }
  float mean = s*(1.0f/768.0f);
  float inv  = rsqrtf(ss*(1.0f/768.0f) - mean*mean + 1e-5f);
  #pragma unroll
  for (int t=0;t<3;++t){
    int c0 = lane*4 + t*256;
    float4 gg = *(const float4*)(nsg + c0);
    float4 bv = *(const float4*)(nsb + c0);
    f16x4 h4;
    h4.x = (f16)((v[t].x-mean)*inv*gg.x + bv.x);
    h4.y = (f16)((v[t].y-mean)*inv*gg.y + bv.y);
    h4.z = (f16)((v[t].z-mean)*inv*gg.z + bv.z);
    h4.w = (f16)((v[t].w-mean)*inv*gg.w + bv.w);
    *(f16x4*)(tmp2 + row*D_DIM + c0) = h4;
  }
}

// ---------- encoder self-attention ----------
__global__ __launch_bounds__(256) void encattn_k(
    const f16* __restrict__ QA, const f16* __restrict__ KA,
    const f16* __restrict__ VA, int QSTR,
    f16* __restrict__ O)
{
  __shared__ float qs[16][68], ks[16][68], vs[16][68], ps[16][20];
  const int b = blockIdx.x, h = blockIdx.y;
  const int tid = threadIdx.x;
  {
    int i = tid>>4, dd=(tid&15)*4;
    size_t base = ((size_t)(b*NSLOT+i))*QSTR + h*64 + dd;
    f16x4 uq = *(const f16x4*)(QA + base);
    f16x4 uk = *(const f16x4*)(KA + base);
    f16x4 uv = *(const f16x4*)(VA + base);
    float4 fq = { (float)uq.x, (float)uq.y, (float)uq.z, (float)uq.w };
    float4 fk = { (float)uk.x, (float)uk.y, (float)uk.z, (float)uk.w };
    float4 fv = { (float)uv.x, (float)uv.y, (float)uv.z, (float)uv.w };
    *(float4*)&qs[i][dd]=fq; *(float4*)&ks[i][dd]=fk; *(float4*)&vs[i][dd]=fv;
  }
  __syncthreads();
  {
    int i = tid>>4, j = tid&15;
    float s=0.f;
    #pragma unroll 8
    for (int d=0; d<64; ++d) s += qs[i][d]*ks[j][d];
    ps[i][j] = s*SCALE_H;
  }
  __syncthreads();
  if (tid < 16){
    int i = tid;
    float mx=-1e30f;
    #pragma unroll
    for (int j=0;j<16;++j) mx = fmaxf(mx, ps[i][j]);
    float sm=0.f;
    #pragma unroll
    for (int j=0;j<16;++j){ float e=__expf(ps[i][j]-mx); ps[i][j]=e; sm+=e; }
    float inv=1.0f/sm;
    #pragma unroll
    for (int j=0;j<16;++j) ps[i][j]*=inv;
  }
  __syncthreads();
  {
    int i = tid>>4, dq=(tid&15)*4;
    float a0=0,a1=0,a2=0,a3=0;
    #pragma unroll
    for (int j=0;j<16;++j){
      float p = ps[i][j];
      a0+=p*vs[j][dq+0]; a1+=p*vs[j][dq+1]; a2+=p*vs[j][dq+2]; a3+=p*vs[j][dq+3];
    }
    size_t base = ((size_t)(b*NSLOT+i))*HDIM + h*64 + dq;
    O[base+0]=(f16)a0; O[base+1]=(f16)a1; O[base+2]=(f16)a2; O[base+3]=(f16)a3;
  }
}

// ---------- f16 transpose: out[C][R] = in[R][C] ----------
__global__ __launch_bounds__(256) void transp_k(
    const f16* __restrict__ in, f16* __restrict__ out, int R, int C)
{
  __shared__ f16 T[64][72];
  const int m0 = blockIdx.x*64, d0 = blockIdx.y*64;
  const int tid = threadIdx.x;
  {
    int r = tid>>2, c = (tid&3)*16;
    const f16* p = in + (size_t)(m0+r)*C + d0 + c;
    *(f16x8*)&T[r][c]   = *(const f16x8*)p;
    *(f16x8*)&T[r][c+8] = *(const f16x8*)(p+8);
  }
  __syncthreads();
  {
    int dd = tid>>2, mq = (tid&3)*16;
    f16 v[16];
    #pragma unroll
    for (int e=0;e<16;++e) v[e] = T[mq+e][dd];
    f16* p = out + (size_t)(d0+dd)*R + m0 + mq;
    *(f16x8*)p     = *(f16x8*)&v[0];
    *(f16x8*)(p+8) = *(f16x8*)&v[8];
  }
}

// ---------- all weight casts/transposes in ONE kernel ----------
__global__ __launch_bounds__(256) void prep_k(
    const float* __restrict__ Wv,   const float* __restrict__ Wq_a,
    const float* __restrict__ Wk_a, const float* __restrict__ Wv_a,
    const float* __restrict__ Wo_a, const float* __restrict__ W1,
    const float* __restrict__ W2,   const float* __restrict__ Wk,
    const float* __restrict__ Wq,
    f16* __restrict__ WvT, f16* __restrict__ WqkvT, f16* __restrict__ WoaT,
    f16* __restrict__ W1T, f16* __restrict__ W2T,
    f16* __restrict__ Wkf, f16* __restrict__ Wqf)
{
  __shared__ float t[32][33];
  int bid = blockIdx.x;
  const float* src; f16* dst; int R, C; bool tr = true;
  if      (bid < 576)  {              src=Wv;   dst=WvT;             R=768;  C=768; }
  else if (bid < 960)  { bid-=576;    src=Wq_a; dst=WqkvT;           R=768;  C=512; }
  else if (bid < 1344) { bid-=960;    src=Wk_a; dst=WqkvT+512*768;   R=768;  C=512; }
  else if (bid < 1728) { bid-=1344;   src=Wv_a; dst=WqkvT+1024*768;  R=768;  C=512; }
  else if (bid < 2112) { bid-=1728;   src=Wo_a; dst=WoaT;            R=512;  C=768; }
  else if (bid < 6720) { bid-=2112;   src=W1;   dst=W1T;             R=768;  C=6144; }
  else if (bid < 9024) { bid-=6720;   src=W2;   dst=W2T;             R=3072; C=768; }
  else if (bid < 9600) { bid-=9024;   src=Wk;   dst=Wkf;             R=768;  C=768; tr=false; }
  else                 { bid-=9600;   src=Wq;   dst=Wqf;             R=768;  C=768; tr=false; }
  const int tpr = C/32;
  const int r0 = (bid / tpr)*32, c0 = (bid % tpr)*32;
  const int lc = threadIdx.x & 31, g8 = threadIdx.x >> 5;
  if (tr){
    #pragma unroll
    for (int s=0;s<4;++s){
      int r = g8*4 + s;
      t[r][lc] = src[(size_t)(r0+r)*C + c0+lc];
    }
    __syncthreads();
    #pragma unroll
    for (int s=0;s<4;++s){
      int c = g8*4 + s;
      dst[(size_t)(c0+c)*R + r0+lc] = (f16)t[lc][c];
    }
  } else {
    #pragma unroll
    for (int s=0;s<4;++s){
      int r = g8*4 + s;
      dst[(size_t)(r0+r)*C + c0+lc] = (f16)src[(size_t)(r0+r)*C + c0+lc];
    }
  }
}

// ---------- attn_map output (rowsum inline) ----------
__global__ __launch_bounds__(256) void attnout_k(
    const f16* __restrict__ attn, const float* __restrict__ rsPart,
    float* __restrict__ out)
{
  __shared__ float rsum[16];
  const int bid = blockIdx.x, tid = threadIdx.x;
  const int b = bid >> 6;
  if (tid < 16){
    float s = 0.f;
    #pragma unroll
    for (int jt=0;jt<16;++jt) s += rsPart[(size_t)((b*16+jt)<<4) + tid];
    rsum[tid] = s;
  }
  __syncthreads();
  int idx = bid*256 + tid;
  int i = idx & 15;
  int j = (idx >> 4) & 1023;
  out[idx] = (float)attn[((size_t)(b*NSLOT)+i)*NTOK + j] / rsum[i];
}

extern "C" void kernel_launch(void* const* d_in, const int* in_sizes, int n_in,
                              void* d_out, int out_size, void* d_ws, size_t ws_size,
                              hipStream_t stream) {
  const float* x        = (const float*)d_in[0];
  const float* noise    = (const float*)d_in[1];
  const float* init_mu  = (const float*)d_in[2];
  const float* init_ls  = (const float*)d_in[3];
  const float* Wk       = (const float*)d_in[4];
  const float* Wv       = (const float*)d_in[5];
  const float* Wq       = (const float*)d_in[6];
  const float* ni_g     = (const float*)d_in[7];
  const float* ni_b     = (const float*)d_in[8];
  const float* ns_g     = (const float*)d_in[9];
  const float* ns_b     = (const float*)d_in[10];
  const float* nica_g   = (const float*)d_in[11];
  const float* nica_b   = (const float*)d_in[12];
  const float* ln1_g    = (const float*)d_in[13];
  const float* ln1_b    = (const float*)d_in[14];
  const float* Wq_a     = (const float*)d_in[15];
  const float* Wk_a     = (const float*)d_in[16];
  const float* Wv_a     = (const float*)d_in[17];
  const float* Wo_a     = (const float*)d_in[18];
  const float* ln2_g    = (const float*)d_in[19];
  const float* ln2_b    = (const float*)d_in[20];
  const float* W1       = (const float*)d_in[21];
  const float* W2       = (const float*)d_in[22];
  const float* lnf_g    = (const float*)d_in[23];
  const float* lnf_b    = (const float*)d_in[24];

  char* w = (char*)d_ws;
  size_t off = 0;
  auto alloc = [&](size_t bytes)->char*{
    char* p = w + off; off += (bytes + 255) & ~(size_t)255; return p;
  };
  f16* xn_h  = (f16*)alloc((size_t)NTOT*D_DIM*2);
  f16* xnT_h = (f16*)alloc((size_t)D_DIM*NTOT*2);
  f16* Wkf   = (f16*)alloc((size_t)768*768*2);
  f16* Wqf   = (f16*)alloc((size_t)768*768*2);
  f16* BtQK  = (f16*)alloc((size_t)768*768*2);
  f16* WvT   = (f16*)alloc((size_t)768*768*2);
  f16* WqkvT = (f16*)alloc((size_t)1536*768*2);
  f16* WoaT  = (f16*)alloc((size_t)768*512*2);
  f16* W1T   = (f16*)alloc((size_t)6144*768*2);
  f16* W2T   = (f16*)alloc((size_t)768*3072*2);
  float* slots = (float*)alloc(512*768*4);
  float* hbuf  = (float*)alloc(512*768*4);
  float* upd   = (float*)alloc(512*768*4);
  f16* tmp_h  = (f16*)alloc(512*768*2);
  f16* tmp2_h = (f16*)alloc(512*768*2);
  f16* q_h    = (f16*)alloc(512*768*2);
  f16* t_h    = (f16*)alloc(512*768*2);
  f16* qkv_h  = (f16*)alloc((size_t)512*1536*2);
  f16* o_h    = (f16*)alloc(512*512*2);
  f16* act_h  = (f16*)alloc((size_t)512*3072*2);
  f16* attn_h = (f16*)alloc((size_t)NB*NSLOT*NTOK*2);
  float* rsPart = (float*)alloc((size_t)32*16*16*4);

  // weight prep: all casts/transposes in one launch
  prep_k<<<10176, 256, 0, stream>>>(Wv, Wq_a, Wk_a, Wv_a, Wo_a, W1, W2, Wk, Wq,
                                    WvT, WqkvT, WoaT, W1T, W2T, Wkf, Wqf);

  // BtQK[f][e] = sum_d Wk[f][d] * Wq[e][d]
  mgemm64_k<1><<<dim3(12, 12, 1), 256, 0, stream>>>(Wkf, Wqf, BtQK, 768, 768, 768, 768);

  // xn = LN(x); xnT = xn^T
  lnw_k<<<NTOT/4, 256, 0, stream>>>(x, ni_g, ni_b, xn_h);
  transp_k<<<dim3(NTOT/64, D_DIM/64), 256, 0, stream>>>(xn_h, xnT_h, NTOT, D_DIM);

  // slots = mu + exp(ls)*noise; tmp2 = LN(slots, ns)
  slotsinit_k<<<128, 256, 0, stream>>>(noise, init_mu, init_ls, ns_g, ns_b,
                                       slots, tmp2_h);

  for (int it=0; it<4; ++it){
    // q_eff = LN(slots,ns) @ (Wq Wk^T)
    mgemm64_k<1><<<dim3(8, 12, 1), 256, 0, stream>>>(tmp2_h, BtQK, q_h, 512, 768, 768, 768);
    // dots = q_eff @ xn^T + inverted softmax
    dots_k<<<dim3(NB, 16), 256, 0, stream>>>(q_h, xn_h, attn_h, rsPart);
    // t = (attn @ xn) / rowsum
    attnv_k<<<dim3(NB, 12), 256, 0, stream>>>(attn_h, rsPart, xnT_h, t_h);
    // upd = t @ Wv
    mgemm64_k<0><<<dim3(8, 12, 1), 256, 0, stream>>>(t_h, WvT, upd, 512, 768, 768, 768);
    // hbuf = LN(slots+upd, nica); tmp = LN(hbuf, ln1)
    lnlnw_k<true><<<128, 256, 0, stream>>>(slots, upd, nica_g, nica_b, ln1_g, ln1_b,
                                           hbuf, tmp_h);
    // qkv = a @ [Wq_a|Wk_a|Wv_a]
    mgemm64_k<1><<<dim3(8, 24, 1), 256, 0, stream>>>(tmp_h, WqkvT, qkv_h, 512, 1536, 768, 768);
    encattn_k<<<dim3(NB, 8), 256, 0, stream>>>(qkv_h, qkv_h + 512, qkv_h + 1024, 1536, o_h);
    // hbuf += o @ Wo_a (split-K=2 atomic, single 256-K step each)
    mgemm64_k<2><<<dim3(8, 12, 2), 256, 0, stream>>>(o_h, WoaT, hbuf, 512, 768, 512, 256);
    // f = LN(hbuf, ln2)
    lnw_k<<<128, 256, 0, stream>>>(hbuf, ln2_g, ln2_b, tmp_h);
    // act = glu(f @ W1)
    w1glu_k<<<dim3(8, 48), 256, 0, stream>>>(tmp_h, W1T, act_h, 512);
    // hbuf += act @ W2 (split-K=4 atomic)
    mgemm64_k<2><<<dim3(8, 12, 4), 256, 0, stream>>>(act_h, W2T, hbuf, 512, 768, 3072, 768);
    // slots = LN(hbuf, lnf) [last iter: straight to d_out]; tmp2 = LN(slots, ns)
    float* out1 = (it==3) ? (float*)d_out : slots;
    lnlnw_k<false><<<128, 256, 0, stream>>>(hbuf, nullptr, lnf_g, lnf_b, ns_g, ns_b,
                                            out1, tmp2_h);
  }

  attnout_k<<<NB*NTOK*NSLOT/256, 256, 0, stream>>>(attn_h, rsPart, (float*)d_out + 512*768);
}